// Round 1
// baseline (4117.546 us; speedup 1.0000x reference)
//
#include <hip/hip_runtime.h>
#include <math.h>

// Problem dims
#define S_N   512
#define WL_N  100
#define E_N   200
#define OC_N  50
#define H_N   400

// ---------------------------------------------------------------------------
// K1: pooled[s][400] = conv_b + (1/L) * sum_{t<L} conv(emb[x])  via prefix sums
// ---------------------------------------------------------------------------
__global__ __launch_bounds__(256, 1)
void pooled_kernel(const int* __restrict__ x, const float* __restrict__ emb,
                   const float* __restrict__ cw0, const float* __restrict__ cw1,
                   const float* __restrict__ cw2, const float* __restrict__ cw3,
                   const float* __restrict__ cw4, const float* __restrict__ cw5,
                   const float* __restrict__ cw6, const float* __restrict__ cw7,
                   const float* __restrict__ conv_b, float* __restrict__ pooled)
{
  const int s = blockIdx.x;
  const int tid = threadIdx.x;
  __shared__ int xr[WL_N];
  __shared__ int Lsh;
  __shared__ float Apart[E_N][17];  // Ssum[e][d+7], d in [-7,7]
  __shared__ float Bpart[E_N][9];   // P[e][d], d in 1..7
  if (tid < WL_N) xr[tid] = x[s * WL_N + tid];
  __syncthreads();
  if (tid == 0) {
    int L = 0;
    for (int t = 0; t < WL_N; ++t) L += (xr[t] != 0) ? 1 : 0;
    Lsh = L;
  }
  __syncthreads();
  const int L = Lsh;  // lengths in [20,100]
  if (tid < E_N) {
    const int e = tid;
    float acc = 0.f;
    for (int t = 0; t < WL_N; ++t) {
      acc += emb[(size_t)xr[t] * E_N + e];
      int m = t + 1;
      if (m <= 7) Bpart[e][m] = acc;                 // P[m], m=1..7
      int rel = m - (L - 7);
      if (rel >= 0 && rel < 15) Apart[e][rel] = acc; // P[L-7+rel]
    }
    const float accF = acc;  // P[100]
    #pragma unroll
    for (int dd = 0; dd < 15; ++dd) {
      int m = L - 7 + dd;
      float A = (m > WL_N) ? accF : Apart[e][dd];
      int d = dd - 7;
      float B = (d > 0) ? Bpart[e][d] : 0.f;
      Apart[e][dd] = A - B;  // sum_{t<L} in[e][t+d], zero-padded
    }
  }
  __syncthreads();
  const float invL = 1.f / (float)L;
  const float* cw[8] = {cw0, cw1, cw2, cw3, cw4, cw5, cw6, cw7};
  for (int c = tid; c < 8 * OC_N; c += 256) {
    int K = c / OC_N, oc = c % OC_N;
    int width = 2 * K + 1;
    const float* w = cw[K] + (size_t)oc * E_N * width;
    float acc = 0.f;
    for (int e = 0; e < E_N; ++e) {
      const float* wr = w + e * width;
      const float* sp = &Apart[e][7 - K];
      for (int k = 0; k < width; ++k) acc += wr[k] * sp[k];
    }
    pooled[(size_t)s * 400 + c] = conv_b[K * OC_N + oc] + acc * invL;
  }
}

// ---------------------------------------------------------------------------
// Generic f32 GEMM: C[M,N] = A[M,K] @ B[N,K]^T + bias[N]  (optional tanh)
// ---------------------------------------------------------------------------
__global__ __launch_bounds__(256, 2)
void gemm_f32(const float* __restrict__ A, int lda,
              const float* __restrict__ Bw, int ldb,
              const float* __restrict__ bias,
              float* __restrict__ C, int ldc,
              int M, int N, int K, int act)
{
  __shared__ float As[16][65];
  __shared__ float Bs[16][65];
  const int bm = blockIdx.y * 64, bn = blockIdx.x * 64;
  const int tid = threadIdx.x;
  const int tr = (tid / 16) * 4, tc = (tid % 16) * 4;
  float acc[4][4] = {};
  for (int k0 = 0; k0 < K; k0 += 16) {
    for (int l = tid; l < 64 * 16; l += 256) {
      int r = l / 16, c = l % 16;
      As[c][r] = (bm + r < M) ? A[(size_t)(bm + r) * lda + k0 + c] : 0.f;
    }
    for (int l = tid; l < 64 * 16; l += 256) {
      int r = l / 16, c = l % 16;
      Bs[c][r] = (bn + r < N) ? Bw[(size_t)(bn + r) * ldb + k0 + c] : 0.f;
    }
    __syncthreads();
    #pragma unroll
    for (int kk = 0; kk < 16; ++kk) {
      float a[4], b[4];
      #pragma unroll
      for (int u = 0; u < 4; ++u) { a[u] = As[kk][tr + u]; b[u] = Bs[kk][tc + u]; }
      #pragma unroll
      for (int u = 0; u < 4; ++u)
        #pragma unroll
        for (int v = 0; v < 4; ++v) acc[u][v] += a[u] * b[v];
    }
    __syncthreads();
  }
  for (int u = 0; u < 4; ++u) {
    int r = bm + tr + u; if (r >= M) continue;
    for (int v = 0; v < 4; ++v) {
      int c = bn + tc + v; if (c >= N) continue;
      float xv = acc[u][v] + (bias ? bias[c] : 0.f);
      if (act == 1) xv = tanhf(xv);
      C[(size_t)r * ldc + c] = xv;
    }
  }
}

// ---------------------------------------------------------------------------
// K3: bidirectional GRU scan. 25 blocks per direction, spin-synced.
// Block b of dir d owns h indices [16b,16b+16); LDS holds its 48 w_hh rows.
// ---------------------------------------------------------------------------
#define GRU_NB 25
#define GRU_CHUNK 16
__global__ __launch_bounds__(768, 1)
void gru_scan_kernel(const float* __restrict__ gi,  // [512][2400] f|b
                     const float* __restrict__ whh_f, const float* __restrict__ bhh_f,
                     const float* __restrict__ whh_b, const float* __restrict__ bhh_b,
                     float* __restrict__ enc,        // [512][800]
                     float* hbuf,                    // [2 dirs][2][400]
                     unsigned int* counters)         // [2]
{
  const int tid = threadIdx.x;
  const int dir = blockIdx.x / GRU_NB;
  const int b   = blockIdx.x % GRU_NB;
  const float* whh = dir ? whh_b : whh_f;
  const float* bhh = dir ? bhh_b : bhh_f;
  float* h2 = hbuf + dir * 800;
  unsigned int* cnt = counters + dir;
  const int i0 = b * GRU_CHUNK;

  __shared__ float wl[48][400];   // 76.8 KB
  __shared__ float bl[48];
  __shared__ float ghs[48];

  for (int l = tid; l < 48 * 400; l += 768) {
    int lr = l / 400, c = l % 400;
    int g = lr / GRU_CHUNK, ii = lr % GRU_CHUNK;
    wl[lr][c] = whh[(size_t)(g * 400 + i0 + ii) * 400 + c];
  }
  if (tid < 48) {
    int g = tid / GRU_CHUNK, ii = tid % GRU_CHUNK;
    bl[tid] = bhh[g * 400 + i0 + ii];
  }
  __syncthreads();

  const int lr = tid >> 4;   // 0..47 (row within our 48)
  const int cc = tid & 15;   // 0..15 (column chunk)
  const int c0 = cc * 25;

  for (int t = 0; t < 512; ++t) {
    if (t > 0) {
      if (tid == 0) {
        while (__hip_atomic_load(cnt, __ATOMIC_ACQUIRE, __HIP_MEMORY_SCOPE_AGENT)
               < (unsigned)(GRU_NB * t)) {
          __builtin_amdgcn_s_sleep(1);
        }
      }
      __syncthreads();
    }
    const float* hcur = h2 + (t & 1) * 400;
    float acc = 0.f;
    #pragma unroll
    for (int j = 0; j < 25; ++j) acc += wl[lr][c0 + j] * hcur[c0 + j];
    acc += __shfl_xor(acc, 1);
    acc += __shfl_xor(acc, 2);
    acc += __shfl_xor(acc, 4);
    acc += __shfl_xor(acc, 8);
    if (cc == 0) ghs[lr] = acc + bl[lr];
    __syncthreads();
    if (tid < GRU_CHUNK) {
      const int t_in = dir ? (511 - t) : t;
      const int i = i0 + tid;
      const float* girow = gi + (size_t)t_in * 2400 + dir * 1200;
      float gir = girow[i], giz = girow[400 + i], gin = girow[800 + i];
      float ghr = ghs[tid], ghz = ghs[16 + tid], ghn = ghs[32 + tid];
      float r = 1.f / (1.f + expf(-(gir + ghr)));
      float z = 1.f / (1.f + expf(-(giz + ghz)));
      float n = tanhf(gin + r * ghn);
      float hprev = hcur[i];
      float hn = (1.f - z) * n + z * hprev;
      h2[((t + 1) & 1) * 400 + i] = hn;
      enc[(size_t)t_in * 800 + dir * 400 + i] = hn;
    }
    __syncthreads();
    if (tid == 0) {
      __threadfence();  // publish h writes device-wide
      __hip_atomic_fetch_add(cnt, 1u, __ATOMIC_RELEASE, __HIP_MEMORY_SCOPE_AGENT);
    }
  }
}

// ---------------------------------------------------------------------------
// K4a: column mean of enc -> mean[800]
// ---------------------------------------------------------------------------
__global__ void mean_kernel(const float* __restrict__ enc, float* __restrict__ mean)
{
  int j = blockIdx.x * 100 + threadIdx.x;
  if (threadIdx.x >= 100) return;
  float s = 0.f;
  for (int t = 0; t < 512; ++t) s += enc[(size_t)t * 800 + j];
  mean[j] = s * (1.f / 512.f);
}

// K4b: doc[r] = tanh(W_doc[r]·mean + b_doc[r]); one block (64 lanes) per row
__global__ void doc_kernel(const float* __restrict__ W_doc, const float* __restrict__ b_doc,
                           const float* __restrict__ mean, float* __restrict__ doc)
{
  int r = blockIdx.x, lane = threadIdx.x;
  float s = 0.f;
  for (int k = lane; k < 800; k += 64) s += W_doc[(size_t)r * 800 + k] * mean[k];
  s += __shfl_xor(s, 1);  s += __shfl_xor(s, 2);  s += __shfl_xor(s, 4);
  s += __shfl_xor(s, 8);  s += __shfl_xor(s, 16); s += __shfl_xor(s, 32);
  if (lane == 0) doc[r] = tanhf(s + b_doc[r]);
}

// K4c: docterm[r] = W_d1[r,1200:1600]·doc + b_d1[r]
__global__ void docterm_kernel(const float* __restrict__ W_d1, const float* __restrict__ b_d1,
                               const float* __restrict__ doc, float* __restrict__ docterm)
{
  int r = blockIdx.x, lane = threadIdx.x;
  float s = 0.f;
  for (int k = lane; k < 400; k += 64) s += W_d1[(size_t)r * 1600 + 1200 + k] * doc[k];
  s += __shfl_xor(s, 1);  s += __shfl_xor(s, 2);  s += __shfl_xor(s, 4);
  s += __shfl_xor(s, 8);  s += __shfl_xor(s, 16); s += __shfl_xor(s, 32);
  if (lane == 0) docterm[r] = s + b_d1[r];
}

// ---------------------------------------------------------------------------
// K6: greedy decoder scan, single block. W_d1[:,800:1200] in registers.
// pre1 already holds W_d1[:, :800]@enc_i + W_d1[:,1200:]@doc + b_d1.
// Rbuf holds tanh(W_r@enc_i + b_r).
// ---------------------------------------------------------------------------
__global__ __launch_bounds__(512, 1)
void decoder_kernel(const float* __restrict__ pre1,  // [512][100]
                    const float* __restrict__ Rbuf,  // [512][400]
                    const float* __restrict__ W_d1,  // [100][1600]
                    const float* __restrict__ W_d2,  // [100]
                    const float* __restrict__ b_d2,  // [1]
                    const int* __restrict__ nos_p,
                    float* __restrict__ out)         // [513]: logp, sels
{
  const int tid = threadIdx.x;
  __shared__ float stage[25 * 400];  // 40 KB staging
  __shared__ float gs[400];
  __shared__ float part[500];
  __shared__ float ds[100];
  __shared__ float selflag;
  __shared__ int scount;
  const int cb = tid / 100;  // 0..4 for tid<500
  const int r  = tid % 100;
  float wreg[80];
  // stage W_d1[:,800:1200] coalesced via LDS, 4 chunks of 25 rows
  for (int ch = 0; ch < 4; ++ch) {
    for (int idx = tid; idx < 25 * 400; idx += 512) {
      int rr = idx / 400, c = idx % 400;
      stage[idx] = W_d1[(size_t)(ch * 25 + rr) * 1600 + 800 + c];
    }
    __syncthreads();
    if (cb < 5 && r >= ch * 25 && r < ch * 25 + 25) {
      #pragma unroll
      for (int j = 0; j < 80; ++j)
        wreg[j] = stage[(r - ch * 25) * 400 + cb * 80 + j];
    }
    __syncthreads();
  }
  if (tid < 400) gs[tid] = 0.f;
  if (tid == 0) scount = 0;
  __syncthreads();
  const int nos = nos_p[0];
  float logp = 0.f;
  for (int i = 0; i < 512; ++i) {
    float rv = 0.f;
    if (tid < 400) rv = Rbuf[(size_t)i * 400 + tid];  // prefetch R row
    if (cb < 5) {
      float accv = 0.f;
      #pragma unroll
      for (int j = 0; j < 80; ++j) accv += wreg[j] * gs[cb * 80 + j];
      part[tid] = accv;
    }
    __syncthreads();
    if (tid < 100) {
      float s = part[tid] + part[100 + tid] + part[200 + tid] + part[300 + tid] + part[400 + tid];
      ds[tid] = tanhf(pre1[(size_t)i * 100 + tid] + s);
    }
    __syncthreads();
    if (tid < 64) {
      float s = W_d2[tid] * ds[tid];
      if (tid < 36) s += W_d2[64 + tid] * ds[64 + tid];
      s += __shfl_xor(s, 1);  s += __shfl_xor(s, 2);  s += __shfl_xor(s, 4);
      s += __shfl_xor(s, 8);  s += __shfl_xor(s, 16); s += __shfl_xor(s, 32);
      if (tid == 0) {
        float p = 1.f / (1.f + expf(-(s + b_d2[0])));
        bool allowed = (nos <= 0) || (scount < nos);
        bool sel = allowed && (p > 0.5f);
        float term = sel ? p : (1.f - p);
        logp += logf(term * 0.99999f + 5e-6f);
        if (sel) scount += 1;
        selflag = sel ? 1.f : 0.f;
        out[1 + i] = selflag;
      }
    }
    __syncthreads();
    if (selflag != 0.f && tid < 400) gs[tid] += rv;
    __syncthreads();
  }
  if (tid == 0) out[0] = logp;
}

// ---------------------------------------------------------------------------
// Launcher
// ---------------------------------------------------------------------------
extern "C" void kernel_launch(void* const* d_in, const int* in_sizes, int n_in,
                              void* d_out, int out_size, void* d_ws, size_t ws_size,
                              hipStream_t stream) {
  const int*   x      = (const int*)  d_in[0];
  const int*   nos    = (const int*)  d_in[1];
  const float* emb    = (const float*)d_in[2];
  const float* cw[8];
  for (int k = 0; k < 8; ++k) cw[k] = (const float*)d_in[3 + k];
  const float* conv_b = (const float*)d_in[11];
  const float* w_ih_f = (const float*)d_in[12];
  const float* w_hh_f = (const float*)d_in[13];
  const float* b_ih_f = (const float*)d_in[14];
  const float* b_hh_f = (const float*)d_in[15];
  const float* w_ih_b = (const float*)d_in[16];
  const float* w_hh_b = (const float*)d_in[17];
  const float* b_ih_b = (const float*)d_in[18];
  const float* b_hh_b = (const float*)d_in[19];
  const float* W_doc  = (const float*)d_in[20];
  const float* b_doc  = (const float*)d_in[21];
  const float* W_d1   = (const float*)d_in[22];
  const float* b_d1   = (const float*)d_in[23];
  const float* W_d2   = (const float*)d_in[24];
  const float* b_d2   = (const float*)d_in[25];
  const float* W_r    = (const float*)d_in[26];
  const float* b_r    = (const float*)d_in[27];

  float* ws = (float*)d_ws;
  const size_t OFF_POOLED  = 0;                       // 512*400
  const size_t OFF_GI      = 204800;                  // 512*2400
  const size_t OFF_ENC     = 1433600;                 // 512*800
  const size_t OFF_R       = 1843200;                 // 512*400
  const size_t OFF_PRE1    = 2048000;                 // 512*100
  const size_t OFF_MEAN    = 2099200;                 // 800
  const size_t OFF_DOC     = 2100000;                 // 400
  const size_t OFF_DOCTERM = 2100400;                 // 100 (+pad)
  const size_t OFF_SYNC    = 2100512;                 // 2 counters (+pad) + 1600 hbuf
  float* pooled  = ws + OFF_POOLED;
  float* gi      = ws + OFF_GI;
  float* enc     = ws + OFF_ENC;
  float* Rbuf    = ws + OFF_R;
  float* pre1    = ws + OFF_PRE1;
  float* mean    = ws + OFF_MEAN;
  float* doc     = ws + OFF_DOC;
  float* docterm = ws + OFF_DOCTERM;
  unsigned int* counters = (unsigned int*)(ws + OFF_SYNC);
  float* hbuf    = ws + OFF_SYNC + 8;

  // zero counters + h0 buffers (re-zeroed on every graph replay)
  hipMemsetAsync(ws + OFF_SYNC, 0, (8 + 1600) * sizeof(float), stream);

  pooled_kernel<<<512, 256, 0, stream>>>(x, emb, cw[0], cw[1], cw[2], cw[3],
                                         cw[4], cw[5], cw[6], cw[7], conv_b, pooled);

  // gi = pooled @ [w_ih_f; w_ih_b]^T + bias  -> [512][2400]
  gemm_f32<<<dim3(19, 8), 256, 0, stream>>>(pooled, 400, w_ih_f, 400, b_ih_f,
                                            gi, 2400, 512, 1200, 400, 0);
  gemm_f32<<<dim3(19, 8), 256, 0, stream>>>(pooled, 400, w_ih_b, 400, b_ih_b,
                                            gi + 1200, 2400, 512, 1200, 400, 0);

  gru_scan_kernel<<<2 * GRU_NB, 768, 0, stream>>>(gi, w_hh_f, b_hh_f, w_hh_b, b_hh_b,
                                                  enc, hbuf, counters);

  mean_kernel<<<8, 128, 0, stream>>>(enc, mean);
  doc_kernel<<<400, 64, 0, stream>>>(W_doc, b_doc, mean, doc);
  docterm_kernel<<<100, 64, 0, stream>>>(W_d1, b_d1, doc, docterm);

  // R = tanh(enc @ W_r^T + b_r)  [512][400]
  gemm_f32<<<dim3(7, 8), 256, 0, stream>>>(enc, 800, W_r, 800, b_r,
                                           Rbuf, 400, 512, 400, 800, 1);
  // pre1 = enc @ W_d1[:, :800]^T + docterm  [512][100]
  gemm_f32<<<dim3(2, 8), 256, 0, stream>>>(enc, 800, W_d1, 1600, docterm,
                                           pre1, 100, 512, 100, 800, 0);

  decoder_kernel<<<1, 512, 0, stream>>>(pre1, Rbuf, W_d1, W_d2, b_d2, nos,
                                        (float*)d_out);
}

// Round 2
// 3286.670 us; speedup vs baseline: 1.2528x; 1.2528x over previous
//
#include <hip/hip_runtime.h>
#include <math.h>

// Problem dims
#define S_N   512
#define WL_N  100
#define E_N   200
#define OC_N  50
#define H_N   400

// ---------------------------------------------------------------------------
// K1: pooled[s][400] = conv_b + (1/L) * sum_{t<L} conv(emb[x])  via prefix sums
// ---------------------------------------------------------------------------
__global__ __launch_bounds__(256, 1)
void pooled_kernel(const int* __restrict__ x, const float* __restrict__ emb,
                   const float* __restrict__ cw0, const float* __restrict__ cw1,
                   const float* __restrict__ cw2, const float* __restrict__ cw3,
                   const float* __restrict__ cw4, const float* __restrict__ cw5,
                   const float* __restrict__ cw6, const float* __restrict__ cw7,
                   const float* __restrict__ conv_b, float* __restrict__ pooled)
{
  const int s = blockIdx.x;
  const int tid = threadIdx.x;
  __shared__ int xr[WL_N];
  __shared__ int Lsh;
  __shared__ float Apart[E_N][17];  // Ssum[e][d+7], d in [-7,7]
  __shared__ float Bpart[E_N][9];   // P[e][d], d in 1..7
  if (tid < WL_N) xr[tid] = x[s * WL_N + tid];
  __syncthreads();
  if (tid == 0) {
    int L = 0;
    for (int t = 0; t < WL_N; ++t) L += (xr[t] != 0) ? 1 : 0;
    Lsh = L;
  }
  __syncthreads();
  const int L = Lsh;  // lengths in [20,100]
  if (tid < E_N) {
    const int e = tid;
    float acc = 0.f;
    for (int t = 0; t < WL_N; ++t) {
      acc += emb[(size_t)xr[t] * E_N + e];
      int m = t + 1;
      if (m <= 7) Bpart[e][m] = acc;                 // P[m], m=1..7
      int rel = m - (L - 7);
      if (rel >= 0 && rel < 15) Apart[e][rel] = acc; // P[L-7+rel]
    }
    const float accF = acc;  // P[100]
    #pragma unroll
    for (int dd = 0; dd < 15; ++dd) {
      int m = L - 7 + dd;
      float A = (m > WL_N) ? accF : Apart[e][dd];
      int d = dd - 7;
      float B = (d > 0) ? Bpart[e][d] : 0.f;
      Apart[e][dd] = A - B;  // sum_{t<L} in[e][t+d], zero-padded
    }
  }
  __syncthreads();
  const float invL = 1.f / (float)L;
  const float* cw[8] = {cw0, cw1, cw2, cw3, cw4, cw5, cw6, cw7};
  for (int c = tid; c < 8 * OC_N; c += 256) {
    int K = c / OC_N, oc = c % OC_N;
    int width = 2 * K + 1;
    const float* w = cw[K] + (size_t)oc * E_N * width;
    float acc = 0.f;
    for (int e = 0; e < E_N; ++e) {
      const float* wr = w + e * width;
      const float* sp = &Apart[e][7 - K];
      for (int k = 0; k < width; ++k) acc += wr[k] * sp[k];
    }
    pooled[(size_t)s * 400 + c] = conv_b[K * OC_N + oc] + acc * invL;
  }
}

// ---------------------------------------------------------------------------
// Generic f32 GEMM: C[M,N] = A[M,K] @ B[N,K]^T + bias[N]  (optional tanh)
// ---------------------------------------------------------------------------
__global__ __launch_bounds__(256, 2)
void gemm_f32(const float* __restrict__ A, int lda,
              const float* __restrict__ Bw, int ldb,
              const float* __restrict__ bias,
              float* __restrict__ C, int ldc,
              int M, int N, int K, int act)
{
  __shared__ float As[16][65];
  __shared__ float Bs[16][65];
  const int bm = blockIdx.y * 64, bn = blockIdx.x * 64;
  const int tid = threadIdx.x;
  const int tr = (tid / 16) * 4, tc = (tid % 16) * 4;
  float acc[4][4] = {};
  for (int k0 = 0; k0 < K; k0 += 16) {
    for (int l = tid; l < 64 * 16; l += 256) {
      int r = l / 16, c = l % 16;
      As[c][r] = (bm + r < M) ? A[(size_t)(bm + r) * lda + k0 + c] : 0.f;
    }
    for (int l = tid; l < 64 * 16; l += 256) {
      int r = l / 16, c = l % 16;
      Bs[c][r] = (bn + r < N) ? Bw[(size_t)(bn + r) * ldb + k0 + c] : 0.f;
    }
    __syncthreads();
    #pragma unroll
    for (int kk = 0; kk < 16; ++kk) {
      float a[4], b[4];
      #pragma unroll
      for (int u = 0; u < 4; ++u) { a[u] = As[kk][tr + u]; b[u] = Bs[kk][tc + u]; }
      #pragma unroll
      for (int u = 0; u < 4; ++u)
        #pragma unroll
        for (int v = 0; v < 4; ++v) acc[u][v] += a[u] * b[v];
    }
    __syncthreads();
  }
  for (int u = 0; u < 4; ++u) {
    int r = bm + tr + u; if (r >= M) continue;
    for (int v = 0; v < 4; ++v) {
      int c = bn + tc + v; if (c >= N) continue;
      float xv = acc[u][v] + (bias ? bias[c] : 0.f);
      if (act == 1) xv = tanhf(xv);
      C[(size_t)r * ldc + c] = xv;
    }
  }
}

// ---------------------------------------------------------------------------
// K3: bidirectional GRU scan. 25 blocks per direction, LLC-rendezvous sync:
// h published via relaxed agent-scope atomic stores (sc1, bypass L2),
// wave-local vmcnt drain, relaxed atomic counter; readers poll relaxed and
// stage h to LDS with coalesced relaxed-agent loads. No threadfence.
// ---------------------------------------------------------------------------
#define GRU_NB 25
#define GRU_CHUNK 16
__global__ __launch_bounds__(768, 1)
void gru_scan_kernel(const float* __restrict__ gi,  // [512][2400] f|b
                     const float* __restrict__ whh_f, const float* __restrict__ bhh_f,
                     const float* __restrict__ whh_b, const float* __restrict__ bhh_b,
                     float* __restrict__ enc,        // [512][800]
                     float* hbuf,                    // [2 dirs][2][400]
                     unsigned int* counters)         // [2]
{
  const int tid = threadIdx.x;
  const int dir = blockIdx.x / GRU_NB;
  const int b   = blockIdx.x % GRU_NB;
  const float* whh = dir ? whh_b : whh_f;
  const float* bhh = dir ? bhh_b : bhh_f;
  float* h2 = hbuf + dir * 800;
  unsigned int* cnt = counters + dir;
  const int i0 = b * GRU_CHUNK;

  __shared__ float wl[48][400];   // 76.8 KB
  __shared__ float hs[400];
  __shared__ float bl[48];
  __shared__ float ghs[48];

  for (int l = tid; l < 48 * 400; l += 768) {
    int lr = l / 400, c = l % 400;
    int g = lr / GRU_CHUNK, ii = lr % GRU_CHUNK;
    wl[lr][c] = whh[(size_t)(g * 400 + i0 + ii) * 400 + c];
  }
  if (tid < 48) {
    int g = tid / GRU_CHUNK, ii = tid % GRU_CHUNK;
    bl[tid] = bhh[g * 400 + i0 + ii];
  }
  __syncthreads();

  const int lr = tid >> 4;   // 0..47 (row within our 48)
  const int cc = tid & 15;   // 0..15 (column chunk)
  const int c0 = cc * 25;

  for (int t = 0; t < 512; ++t) {
    const int t_in = dir ? (511 - t) : t;
    // prefetch gi row for this step (independent of sync)
    float gir = 0.f, giz = 0.f, gin = 0.f;
    if (tid < GRU_CHUNK) {
      const float* girow = gi + (size_t)t_in * 2400 + dir * 1200;
      gir = girow[i0 + tid]; giz = girow[400 + i0 + tid]; gin = girow[800 + i0 + tid];
    }
    if (t > 0) {
      if (tid == 0) {
        while (__hip_atomic_load(cnt, __ATOMIC_RELAXED, __HIP_MEMORY_SCOPE_AGENT)
               < (unsigned)(GRU_NB * t)) {
          __builtin_amdgcn_s_sleep(1);
        }
      }
      __syncthreads();   // [A] step t-1 published by all blocks
    }
    const float* hcur = h2 + (t & 1) * 400;
    // stage h (wave 0, coalesced sc1 loads bypassing stale L2) into LDS
    if (tid < 64) {
      float hv[7];
      #pragma unroll
      for (int k = 0; k < 7; ++k) {
        int idx = tid + 64 * k;
        if (idx < 400)
          hv[k] = __hip_atomic_load(hcur + idx, __ATOMIC_RELAXED, __HIP_MEMORY_SCOPE_AGENT);
      }
      #pragma unroll
      for (int k = 0; k < 7; ++k) {
        int idx = tid + 64 * k;
        if (idx < 400) hs[idx] = hv[k];
      }
    }
    __syncthreads();     // [B] hs ready
    float acc = 0.f;
    #pragma unroll
    for (int j = 0; j < 25; ++j) acc += wl[lr][c0 + j] * hs[c0 + j];
    acc += __shfl_xor(acc, 1);
    acc += __shfl_xor(acc, 2);
    acc += __shfl_xor(acc, 4);
    acc += __shfl_xor(acc, 8);
    if (cc == 0) ghs[lr] = acc + bl[lr];
    __syncthreads();     // [C] ghs ready
    if (tid < GRU_CHUNK) {
      const int i = i0 + tid;
      float ghr = ghs[tid], ghz = ghs[16 + tid], ghn = ghs[32 + tid];
      float r = 1.f / (1.f + expf(-(gir + ghr)));
      float z = 1.f / (1.f + expf(-(giz + ghz)));
      float n = tanhf(gin + r * ghn);
      float hprev = hs[i];
      float hn = (1.f - z) * n + z * hprev;
      __hip_atomic_store(h2 + ((t + 1) & 1) * 400 + i, hn,
                         __ATOMIC_RELAXED, __HIP_MEMORY_SCOPE_AGENT);
      enc[(size_t)t_in * 800 + dir * 400 + i] = hn;
    }
    // h writers (tid<16) and tid==0 are all in wave 0: a wave-local vmcnt
    // drain makes the sc1 stores LLC-visible before the counter bump.
    if (tid == 0) {
      asm volatile("s_waitcnt vmcnt(0)" ::: "memory");
      __hip_atomic_fetch_add(cnt, 1u, __ATOMIC_RELAXED, __HIP_MEMORY_SCOPE_AGENT);
    }
    __syncthreads();     // [D] keep hs stable until all waves done with it
  }
}

// ---------------------------------------------------------------------------
// K4a: column mean of enc -> mean[800]
// ---------------------------------------------------------------------------
__global__ void mean_kernel(const float* __restrict__ enc, float* __restrict__ mean)
{
  int j = blockIdx.x * 100 + threadIdx.x;
  if (threadIdx.x >= 100) return;
  float s = 0.f;
  for (int t = 0; t < 512; ++t) s += enc[(size_t)t * 800 + j];
  mean[j] = s * (1.f / 512.f);
}

// K4b: doc[r] = tanh(W_doc[r]·mean + b_doc[r]); one block (64 lanes) per row
__global__ void doc_kernel(const float* __restrict__ W_doc, const float* __restrict__ b_doc,
                           const float* __restrict__ mean, float* __restrict__ doc)
{
  int r = blockIdx.x, lane = threadIdx.x;
  float s = 0.f;
  for (int k = lane; k < 800; k += 64) s += W_doc[(size_t)r * 800 + k] * mean[k];
  s += __shfl_xor(s, 1);  s += __shfl_xor(s, 2);  s += __shfl_xor(s, 4);
  s += __shfl_xor(s, 8);  s += __shfl_xor(s, 16); s += __shfl_xor(s, 32);
  if (lane == 0) doc[r] = tanhf(s + b_doc[r]);
}

// K4c: docterm[r] = W_d1[r,1200:1600]·doc + b_d1[r]
__global__ void docterm_kernel(const float* __restrict__ W_d1, const float* __restrict__ b_d1,
                               const float* __restrict__ doc, float* __restrict__ docterm)
{
  int r = blockIdx.x, lane = threadIdx.x;
  float s = 0.f;
  for (int k = lane; k < 400; k += 64) s += W_d1[(size_t)r * 1600 + 1200 + k] * doc[k];
  s += __shfl_xor(s, 1);  s += __shfl_xor(s, 2);  s += __shfl_xor(s, 4);
  s += __shfl_xor(s, 8);  s += __shfl_xor(s, 16); s += __shfl_xor(s, 32);
  if (lane == 0) docterm[r] = s + b_d1[r];
}

// ---------------------------------------------------------------------------
// K6: greedy decoder scan — single wave, barrier-free.
// pre1[i] = W_d1[:, :800]@enc_i + W_d1[:,1200:]@doc + b_d1   (precomputed)
// Qb[i]   = W_d1[:,800:1200] @ tanh(W_r@enc_i + b_r)          (precomputed)
// Running q = W_d1mid @ g updated incrementally on selection.
// ---------------------------------------------------------------------------
__global__ __launch_bounds__(64, 1)
void decoder_kernel(const float* __restrict__ pre1,  // [512][100]
                    const float* __restrict__ Qb,    // [512][100]
                    const float* __restrict__ W_d2,  // [100]
                    const float* __restrict__ b_d2,  // [1]
                    const int* __restrict__ nos_p,
                    float* __restrict__ out)         // [513]: logp, sels
{
  const int j = threadIdx.x;         // 0..63
  const bool hi = (j < 36);          // second element j+64 valid
  const int j2 = hi ? j + 64 : j;    // safe address
  const float w2a = W_d2[j];
  const float w2b = hi ? W_d2[j + 64] : 0.f;
  const float bd2 = b_d2[0];
  const int nos = nos_p[0];
  float q0 = 0.f, q1 = 0.f;
  int count = 0;
  float logp = 0.f;
  float pa = pre1[j], pb = pre1[j2];   // prefetch row 0
  for (int i = 0; i < 512; ++i) {
    float d0 = tanhf(pa + q0);
    float d1 = tanhf(pb + q1);
    if (i + 1 < 512) {                 // prefetch next row
      pa = pre1[(size_t)(i + 1) * 100 + j];
      pb = pre1[(size_t)(i + 1) * 100 + j2];
    }
    float s = w2a * d0 + w2b * d1;
    s += __shfl_xor(s, 1);  s += __shfl_xor(s, 2);  s += __shfl_xor(s, 4);
    s += __shfl_xor(s, 8);  s += __shfl_xor(s, 16); s += __shfl_xor(s, 32);
    float p = 1.f / (1.f + expf(-(s + bd2)));
    bool allowed = (nos <= 0) || (count < nos);
    bool sel = allowed && (p > 0.5f);
    float term = sel ? p : (1.f - p);
    logp += logf(term * 0.99999f + 5e-6f);
    if (sel) {
      count++;
      q0 += Qb[(size_t)i * 100 + j];
      if (hi) q1 += Qb[(size_t)i * 100 + j + 64];
    }
    if (j == 0) out[1 + i] = sel ? 1.f : 0.f;
  }
  if (j == 0) out[0] = logp;
}

// ---------------------------------------------------------------------------
// Launcher
// ---------------------------------------------------------------------------
extern "C" void kernel_launch(void* const* d_in, const int* in_sizes, int n_in,
                              void* d_out, int out_size, void* d_ws, size_t ws_size,
                              hipStream_t stream) {
  const int*   x      = (const int*)  d_in[0];
  const int*   nos    = (const int*)  d_in[1];
  const float* emb    = (const float*)d_in[2];
  const float* cw[8];
  for (int k = 0; k < 8; ++k) cw[k] = (const float*)d_in[3 + k];
  const float* conv_b = (const float*)d_in[11];
  const float* w_ih_f = (const float*)d_in[12];
  const float* w_hh_f = (const float*)d_in[13];
  const float* b_ih_f = (const float*)d_in[14];
  const float* b_hh_f = (const float*)d_in[15];
  const float* w_ih_b = (const float*)d_in[16];
  const float* w_hh_b = (const float*)d_in[17];
  const float* b_ih_b = (const float*)d_in[18];
  const float* b_hh_b = (const float*)d_in[19];
  const float* W_doc  = (const float*)d_in[20];
  const float* b_doc  = (const float*)d_in[21];
  const float* W_d1   = (const float*)d_in[22];
  const float* b_d1   = (const float*)d_in[23];
  const float* W_d2   = (const float*)d_in[24];
  const float* b_d2   = (const float*)d_in[25];
  const float* W_r    = (const float*)d_in[26];
  const float* b_r    = (const float*)d_in[27];

  float* ws = (float*)d_ws;
  const size_t OFF_POOLED  = 0;                       // 512*400
  const size_t OFF_GI      = 204800;                  // 512*2400 (reused as Qbuf later)
  const size_t OFF_ENC     = 1433600;                 // 512*800
  const size_t OFF_R       = 1843200;                 // 512*400
  const size_t OFF_PRE1    = 2048000;                 // 512*100
  const size_t OFF_MEAN    = 2099200;                 // 800
  const size_t OFF_DOC     = 2100000;                 // 400
  const size_t OFF_DOCTERM = 2100400;                 // 100 (+pad)
  const size_t OFF_SYNC    = 2100512;                 // 2 counters (+pad) + 1600 hbuf
  float* pooled  = ws + OFF_POOLED;
  float* gi      = ws + OFF_GI;
  float* enc     = ws + OFF_ENC;
  float* Rbuf    = ws + OFF_R;
  float* pre1    = ws + OFF_PRE1;
  float* mean    = ws + OFF_MEAN;
  float* doc     = ws + OFF_DOC;
  float* docterm = ws + OFF_DOCTERM;
  unsigned int* counters = (unsigned int*)(ws + OFF_SYNC);
  float* hbuf    = ws + OFF_SYNC + 8;
  float* Qbuf    = ws + OFF_GI;     // gi dead after GRU; reuse for Q

  // zero counters + h0 buffers (re-zeroed on every graph replay)
  hipMemsetAsync(ws + OFF_SYNC, 0, (8 + 1600) * sizeof(float), stream);

  pooled_kernel<<<512, 256, 0, stream>>>(x, emb, cw[0], cw[1], cw[2], cw[3],
                                         cw[4], cw[5], cw[6], cw[7], conv_b, pooled);

  // gi = pooled @ [w_ih_f; w_ih_b]^T + bias  -> [512][2400]
  gemm_f32<<<dim3(19, 8), 256, 0, stream>>>(pooled, 400, w_ih_f, 400, b_ih_f,
                                            gi, 2400, 512, 1200, 400, 0);
  gemm_f32<<<dim3(19, 8), 256, 0, stream>>>(pooled, 400, w_ih_b, 400, b_ih_b,
                                            gi + 1200, 2400, 512, 1200, 400, 0);

  gru_scan_kernel<<<2 * GRU_NB, 768, 0, stream>>>(gi, w_hh_f, b_hh_f, w_hh_b, b_hh_b,
                                                  enc, hbuf, counters);

  mean_kernel<<<8, 128, 0, stream>>>(enc, mean);
  doc_kernel<<<400, 64, 0, stream>>>(W_doc, b_doc, mean, doc);
  docterm_kernel<<<100, 64, 0, stream>>>(W_d1, b_d1, doc, docterm);

  // R = tanh(enc @ W_r^T + b_r)  [512][400]
  gemm_f32<<<dim3(7, 8), 256, 0, stream>>>(enc, 800, W_r, 800, b_r,
                                           Rbuf, 400, 512, 400, 800, 1);
  // Q = R @ W_d1[:,800:1200]^T  [512][100]
  gemm_f32<<<dim3(2, 8), 256, 0, stream>>>(Rbuf, 400, W_d1 + 800, 1600, nullptr,
                                           Qbuf, 100, 512, 100, 400, 0);
  // pre1 = enc @ W_d1[:, :800]^T + docterm  [512][100]
  gemm_f32<<<dim3(2, 8), 256, 0, stream>>>(enc, 800, W_d1, 1600, docterm,
                                           pre1, 100, 512, 100, 800, 0);

  decoder_kernel<<<1, 64, 0, stream>>>(pre1, Qbuf, W_d2, b_d2, nos,
                                       (float*)d_out);
}

// Round 3
// 2537.500 us; speedup vs baseline: 1.6227x; 1.2952x over previous
//
#include <hip/hip_runtime.h>
#include <math.h>

// Problem dims
#define S_N   512
#define WL_N  100
#define E_N   200
#define OC_N  50
#define H_N   400

// ---------------------------------------------------------------------------
// K1: pooled[s][400] = conv_b + (1/L) * sum_{t<L} conv(emb[x])  via prefix sums
// ---------------------------------------------------------------------------
__global__ __launch_bounds__(256, 1)
void pooled_kernel(const int* __restrict__ x, const float* __restrict__ emb,
                   const float* __restrict__ cw0, const float* __restrict__ cw1,
                   const float* __restrict__ cw2, const float* __restrict__ cw3,
                   const float* __restrict__ cw4, const float* __restrict__ cw5,
                   const float* __restrict__ cw6, const float* __restrict__ cw7,
                   const float* __restrict__ conv_b, float* __restrict__ pooled)
{
  const int s = blockIdx.x;
  const int tid = threadIdx.x;
  __shared__ int xr[WL_N];
  __shared__ int Lsh;
  __shared__ float Apart[E_N][17];  // Ssum[e][d+7], d in [-7,7]
  __shared__ float Bpart[E_N][9];   // P[e][d], d in 1..7
  if (tid < WL_N) xr[tid] = x[s * WL_N + tid];
  __syncthreads();
  if (tid == 0) {
    int L = 0;
    for (int t = 0; t < WL_N; ++t) L += (xr[t] != 0) ? 1 : 0;
    Lsh = L;
  }
  __syncthreads();
  const int L = Lsh;  // lengths in [20,100]
  if (tid < E_N) {
    const int e = tid;
    float acc = 0.f;
    for (int t = 0; t < WL_N; ++t) {
      acc += emb[(size_t)xr[t] * E_N + e];
      int m = t + 1;
      if (m <= 7) Bpart[e][m] = acc;                 // P[m], m=1..7
      int rel = m - (L - 7);
      if (rel >= 0 && rel < 15) Apart[e][rel] = acc; // P[L-7+rel]
    }
    const float accF = acc;  // P[100]
    #pragma unroll
    for (int dd = 0; dd < 15; ++dd) {
      int m = L - 7 + dd;
      float A = (m > WL_N) ? accF : Apart[e][dd];
      int d = dd - 7;
      float B = (d > 0) ? Bpart[e][d] : 0.f;
      Apart[e][dd] = A - B;  // sum_{t<L} in[e][t+d], zero-padded
    }
  }
  __syncthreads();
  const float invL = 1.f / (float)L;
  const float* cw[8] = {cw0, cw1, cw2, cw3, cw4, cw5, cw6, cw7};
  for (int c = tid; c < 8 * OC_N; c += 256) {
    int K = c / OC_N, oc = c % OC_N;
    int width = 2 * K + 1;
    const float* w = cw[K] + (size_t)oc * E_N * width;
    float acc = 0.f;
    for (int e = 0; e < E_N; ++e) {
      const float* wr = w + e * width;
      const float* sp = &Apart[e][7 - K];
      for (int k = 0; k < width; ++k) acc += wr[k] * sp[k];
    }
    pooled[(size_t)s * 400 + c] = conv_b[K * OC_N + oc] + acc * invL;
  }
}

// ---------------------------------------------------------------------------
// Generic f32 GEMM: C[M,N] = A[M,K] @ B[N,K]^T + bias[N]  (optional tanh)
// ---------------------------------------------------------------------------
__global__ __launch_bounds__(256, 2)
void gemm_f32(const float* __restrict__ A, int lda,
              const float* __restrict__ Bw, int ldb,
              const float* __restrict__ bias,
              float* __restrict__ C, int ldc,
              int M, int N, int K, int act)
{
  __shared__ float As[16][65];
  __shared__ float Bs[16][65];
  const int bm = blockIdx.y * 64, bn = blockIdx.x * 64;
  const int tid = threadIdx.x;
  const int tr = (tid / 16) * 4, tc = (tid % 16) * 4;
  float acc[4][4] = {};
  for (int k0 = 0; k0 < K; k0 += 16) {
    for (int l = tid; l < 64 * 16; l += 256) {
      int r = l / 16, c = l % 16;
      As[c][r] = (bm + r < M) ? A[(size_t)(bm + r) * lda + k0 + c] : 0.f;
    }
    for (int l = tid; l < 64 * 16; l += 256) {
      int r = l / 16, c = l % 16;
      Bs[c][r] = (bn + r < N) ? Bw[(size_t)(bn + r) * ldb + k0 + c] : 0.f;
    }
    __syncthreads();
    #pragma unroll
    for (int kk = 0; kk < 16; ++kk) {
      float a[4], b[4];
      #pragma unroll
      for (int u = 0; u < 4; ++u) { a[u] = As[kk][tr + u]; b[u] = Bs[kk][tc + u]; }
      #pragma unroll
      for (int u = 0; u < 4; ++u)
        #pragma unroll
        for (int v = 0; v < 4; ++v) acc[u][v] += a[u] * b[v];
    }
    __syncthreads();
  }
  for (int u = 0; u < 4; ++u) {
    int r = bm + tr + u; if (r >= M) continue;
    for (int v = 0; v < 4; ++v) {
      int c = bn + tc + v; if (c >= N) continue;
      float xv = acc[u][v] + (bias ? bias[c] : 0.f);
      if (act == 1) xv = tanhf(xv);
      C[(size_t)r * ldc + c] = xv;
    }
  }
}

// ---------------------------------------------------------------------------
// K3: bidirectional GRU scan, 25 blocks x 256 threads per direction.
// Sync: h published as (tag<<32 | f32) via relaxed agent-scope 64-bit atomic
// stores (LLC-direct). Readers poll the tagged data itself — no counter, no
// RMW, no fence. Parity double-buffer; exact-tag check (stale = t-2 only).
// Thread (i=tid>>4, cc=tid&15) computes all 3 gate rows for h[i0+i], cols
// [cc*25, cc*25+25) -> gates meet in lane cc==0 -> ONE barrier per step.
// ---------------------------------------------------------------------------
#define GRU_NB 25
#define GRU_CHUNK 16
__global__ __launch_bounds__(256, 1)
void gru_scan_kernel(const float* __restrict__ gi,  // [512][2400] f|b
                     const float* __restrict__ whh_f, const float* __restrict__ bhh_f,
                     const float* __restrict__ whh_b, const float* __restrict__ bhh_b,
                     float* __restrict__ enc,                  // [512][800]
                     unsigned long long* __restrict__ hbuf)    // [2 dirs][2][400]
{
  const int tid = threadIdx.x;
  const int dir = blockIdx.x / GRU_NB;
  const int b   = blockIdx.x % GRU_NB;
  const float* whh = dir ? whh_b : whh_f;
  const float* bhh = dir ? bhh_b : bhh_f;
  unsigned long long* hb = hbuf + (size_t)dir * 800;
  const int i0 = b * GRU_CHUNK;

  __shared__ float wl[48][400];   // 76.8 KB
  __shared__ float hs[400];

  // load this block's 48 w_hh rows (rows: gate g in {r,z,n} x 16 h-indices)
  for (int l = tid; l < 48 * 400; l += 256) {
    int lr = l / 400, c = l % 400;
    int g = lr / GRU_CHUNK, ii = lr % GRU_CHUNK;
    wl[lr][c] = whh[(size_t)(g * 400 + i0 + ii) * 400 + c];
  }

  const int i  = tid >> 4;   // 0..15: which h-index in our chunk
  const int cc = tid & 15;   // 0..15: column chunk
  const int c0 = cc * 25;

  float blr = 0.f, blz = 0.f, bln = 0.f;
  if (cc == 0) {
    blr = bhh[i0 + i];
    blz = bhh[400 + i0 + i];
    bln = bhh[800 + i0 + i];
  }
  __syncthreads();

  const int idx0 = tid;        // always < 400
  const int idx1 = tid + 256;  // valid if < 400

  for (int t = 0; t < 512; ++t) {
    const int t_in = dir ? (511 - t) : t;
    // prefetch gi row for this step (independent of sync)
    float gir = 0.f, giz = 0.f, gin = 0.f;
    if (cc == 0) {
      const float* girow = gi + (size_t)t_in * 2400 + dir * 1200 + i0 + i;
      gir = girow[0]; giz = girow[400]; gin = girow[800];
    }
    // poll tagged h of step t (slot t&1); every thread covers <=2 entries
    {
      const unsigned long long* src = hb + (t & 1) * 400;
      const unsigned want = (unsigned)t;
      unsigned long long u0, u1 = 0;
      for (;;) {
        bool ok = true;
        u0 = __hip_atomic_load(src + idx0, __ATOMIC_RELAXED, __HIP_MEMORY_SCOPE_AGENT);
        ok &= ((unsigned)(u0 >> 32) == want);
        if (idx1 < 400) {
          u1 = __hip_atomic_load(src + idx1, __ATOMIC_RELAXED, __HIP_MEMORY_SCOPE_AGENT);
          ok &= ((unsigned)(u1 >> 32) == want);
        }
        if (__all(ok)) break;
        __builtin_amdgcn_s_sleep(1);
      }
      hs[idx0] = __uint_as_float((unsigned)u0);
      if (idx1 < 400) hs[idx1] = __uint_as_float((unsigned)u1);
    }
    __syncthreads();   // hs ready (the ONLY barrier per step)

    // 3 gate partial dots over our 25-column chunk
    float a0 = 0.f, a1 = 0.f, a2 = 0.f;
    #pragma unroll
    for (int j = 0; j < 25; ++j) {
      float hv = hs[c0 + j];
      a0 += wl[i][c0 + j] * hv;
      a1 += wl[16 + i][c0 + j] * hv;
      a2 += wl[32 + i][c0 + j] * hv;
    }
    #pragma unroll
    for (int m = 1; m <= 8; m <<= 1) {
      a0 += __shfl_xor(a0, m);
      a1 += __shfl_xor(a1, m);
      a2 += __shfl_xor(a2, m);
    }
    if (cc == 0) {
      float r = 1.f / (1.f + expf(-(gir + a0 + blr)));
      float z = 1.f / (1.f + expf(-(giz + a1 + blz)));
      float n = tanhf(gin + r * (a2 + bln));
      float hprev = hs[i0 + i];
      float hn = (1.f - z) * n + z * hprev;
      unsigned long long pk =
          ((unsigned long long)(unsigned)(t + 1) << 32) | (unsigned long long)__float_as_uint(hn);
      __hip_atomic_store(hb + ((t + 1) & 1) * 400 + i0 + i, pk,
                         __ATOMIC_RELAXED, __HIP_MEMORY_SCOPE_AGENT);
      enc[(size_t)t_in * 800 + dir * 400 + i0 + i] = hn;
    }
    // no second barrier: a wave can only overwrite hs after its poll for t+1
    // succeeds, which requires every wave of every block to have published t+1
    // (i.e. finished reading hs for step t).
  }
}

// ---------------------------------------------------------------------------
// K4a: column mean of enc -> mean[800]. 50 blocks x 256 thr (16 cols each).
// ---------------------------------------------------------------------------
__global__ void mean_kernel(const float* __restrict__ enc, float* __restrict__ mean)
{
  __shared__ float part[16][17];
  const int c = threadIdx.x & 15, rch = threadIdx.x >> 4;
  const int col = blockIdx.x * 16 + c;
  float s = 0.f;
  for (int r = rch; r < 512; r += 16) s += enc[(size_t)r * 800 + col];
  part[rch][c] = s;
  __syncthreads();
  if (threadIdx.x < 16) {
    float tt = 0.f;
    #pragma unroll
    for (int k = 0; k < 16; ++k) tt += part[k][threadIdx.x];
    mean[blockIdx.x * 16 + threadIdx.x] = tt * (1.f / 512.f);
  }
}

// K4b: doc[r] = tanh(W_doc[r]·mean + b_doc[r]); one block (64 lanes) per row
__global__ void doc_kernel(const float* __restrict__ W_doc, const float* __restrict__ b_doc,
                           const float* __restrict__ mean, float* __restrict__ doc)
{
  int r = blockIdx.x, lane = threadIdx.x;
  float s = 0.f;
  for (int k = lane; k < 800; k += 64) s += W_doc[(size_t)r * 800 + k] * mean[k];
  s += __shfl_xor(s, 1);  s += __shfl_xor(s, 2);  s += __shfl_xor(s, 4);
  s += __shfl_xor(s, 8);  s += __shfl_xor(s, 16); s += __shfl_xor(s, 32);
  if (lane == 0) doc[r] = tanhf(s + b_doc[r]);
}

// K4c: docterm[r] = W_d1[r,1200:1600]·doc + b_d1[r]
__global__ void docterm_kernel(const float* __restrict__ W_d1, const float* __restrict__ b_d1,
                               const float* __restrict__ doc, float* __restrict__ docterm)
{
  int r = blockIdx.x, lane = threadIdx.x;
  float s = 0.f;
  for (int k = lane; k < 400; k += 64) s += W_d1[(size_t)r * 1600 + 1200 + k] * doc[k];
  s += __shfl_xor(s, 1);  s += __shfl_xor(s, 2);  s += __shfl_xor(s, 4);
  s += __shfl_xor(s, 8);  s += __shfl_xor(s, 16); s += __shfl_xor(s, 32);
  if (lane == 0) docterm[r] = s + b_d1[r];
}

// ---------------------------------------------------------------------------
// K6: greedy decoder scan — single wave, barrier-free.
// pre1[i] = W_d1[:, :800]@enc_i + W_d1[:,1200:]@doc + b_d1   (precomputed)
// Qb[i]   = W_d1[:,800:1200] @ tanh(W_r@enc_i + b_r)          (precomputed)
// Running q = W_d1mid @ g updated incrementally on selection.
// ---------------------------------------------------------------------------
__global__ __launch_bounds__(64, 1)
void decoder_kernel(const float* __restrict__ pre1,  // [512][100]
                    const float* __restrict__ Qb,    // [512][100]
                    const float* __restrict__ W_d2,  // [100]
                    const float* __restrict__ b_d2,  // [1]
                    const int* __restrict__ nos_p,
                    float* __restrict__ out)         // [513]: logp, sels
{
  const int j = threadIdx.x;         // 0..63
  const bool hi = (j < 36);          // second element j+64 valid
  const int j2 = hi ? j + 64 : j;    // safe address
  const float w2a = W_d2[j];
  const float w2b = hi ? W_d2[j + 64] : 0.f;
  const float bd2 = b_d2[0];
  const int nos = nos_p[0];
  float q0 = 0.f, q1 = 0.f;
  int count = 0;
  float logp = 0.f;
  float pa = pre1[j], pb = pre1[j2];   // prefetch row 0
  for (int i = 0; i < 512; ++i) {
    float d0 = tanhf(pa + q0);
    float d1 = tanhf(pb + q1);
    if (i + 1 < 512) {                 // prefetch next row
      pa = pre1[(size_t)(i + 1) * 100 + j];
      pb = pre1[(size_t)(i + 1) * 100 + j2];
    }
    float s = w2a * d0 + w2b * d1;
    s += __shfl_xor(s, 1);  s += __shfl_xor(s, 2);  s += __shfl_xor(s, 4);
    s += __shfl_xor(s, 8);  s += __shfl_xor(s, 16); s += __shfl_xor(s, 32);
    float p = 1.f / (1.f + expf(-(s + bd2)));
    bool allowed = (nos <= 0) || (count < nos);
    bool sel = allowed && (p > 0.5f);
    float term = sel ? p : (1.f - p);
    logp += logf(term * 0.99999f + 5e-6f);
    if (sel) {
      count++;
      q0 += Qb[(size_t)i * 100 + j];
      if (hi) q1 += Qb[(size_t)i * 100 + j + 64];
    }
    if (j == 0) out[1 + i] = sel ? 1.f : 0.f;
  }
  if (j == 0) out[0] = logp;
}

// ---------------------------------------------------------------------------
// Launcher
// ---------------------------------------------------------------------------
extern "C" void kernel_launch(void* const* d_in, const int* in_sizes, int n_in,
                              void* d_out, int out_size, void* d_ws, size_t ws_size,
                              hipStream_t stream) {
  const int*   x      = (const int*)  d_in[0];
  const int*   nos    = (const int*)  d_in[1];
  const float* emb    = (const float*)d_in[2];
  const float* cw[8];
  for (int k = 0; k < 8; ++k) cw[k] = (const float*)d_in[3 + k];
  const float* conv_b = (const float*)d_in[11];
  const float* w_ih_f = (const float*)d_in[12];
  const float* w_hh_f = (const float*)d_in[13];
  const float* b_ih_f = (const float*)d_in[14];
  const float* b_hh_f = (const float*)d_in[15];
  const float* w_ih_b = (const float*)d_in[16];
  const float* w_hh_b = (const float*)d_in[17];
  const float* b_ih_b = (const float*)d_in[18];
  const float* b_hh_b = (const float*)d_in[19];
  const float* W_doc  = (const float*)d_in[20];
  const float* b_doc  = (const float*)d_in[21];
  const float* W_d1   = (const float*)d_in[22];
  const float* b_d1   = (const float*)d_in[23];
  const float* W_d2   = (const float*)d_in[24];
  const float* b_d2   = (const float*)d_in[25];
  const float* W_r    = (const float*)d_in[26];
  const float* b_r    = (const float*)d_in[27];

  float* ws = (float*)d_ws;
  const size_t OFF_POOLED  = 0;                       // 512*400 (reused: hbuf after gi gemms)
  const size_t OFF_GI      = 204800;                  // 512*2400 (reused as Qbuf later)
  const size_t OFF_ENC     = 1433600;                 // 512*800
  const size_t OFF_R       = 1843200;                 // 512*400
  const size_t OFF_PRE1    = 2048000;                 // 512*100
  const size_t OFF_MEAN    = 2099200;                 // 800
  const size_t OFF_DOC     = 2100000;                 // 400
  const size_t OFF_DOCTERM = 2100400;                 // 100 (+pad)
  float* pooled  = ws + OFF_POOLED;
  float* gi      = ws + OFF_GI;
  float* enc     = ws + OFF_ENC;
  float* Rbuf    = ws + OFF_R;
  float* pre1    = ws + OFF_PRE1;
  float* mean    = ws + OFF_MEAN;
  float* doc     = ws + OFF_DOC;
  float* docterm = ws + OFF_DOCTERM;
  float* Qbuf    = ws + OFF_GI;     // gi dead after GRU; reuse for Q
  // hbuf aliases the pooled region (dead after the gi GEMMs): 2*2*400 u64 = 25.6 KB
  unsigned long long* hbuf = (unsigned long long*)(ws + OFF_POOLED);

  pooled_kernel<<<512, 256, 0, stream>>>(x, emb, cw[0], cw[1], cw[2], cw[3],
                                         cw[4], cw[5], cw[6], cw[7], conv_b, pooled);

  // gi = pooled @ [w_ih_f; w_ih_b]^T + bias  -> [512][2400]
  gemm_f32<<<dim3(19, 8), 256, 0, stream>>>(pooled, 400, w_ih_f, 400, b_ih_f,
                                            gi, 2400, 512, 1200, 400, 0);
  gemm_f32<<<dim3(19, 8), 256, 0, stream>>>(pooled, 400, w_ih_b, 400, b_ih_b,
                                            gi + 1200, 2400, 512, 1200, 400, 0);

  // zero tagged h buffers (pooled region is dead now); tag 0 == h_0 = 0
  hipMemsetAsync(hbuf, 0, 2 * 2 * 400 * sizeof(unsigned long long), stream);

  gru_scan_kernel<<<2 * GRU_NB, 256, 0, stream>>>(gi, w_hh_f, b_hh_f, w_hh_b, b_hh_b,
                                                  enc, hbuf);

  mean_kernel<<<50, 256, 0, stream>>>(enc, mean);
  doc_kernel<<<400, 64, 0, stream>>>(W_doc, b_doc, mean, doc);
  docterm_kernel<<<100, 64, 0, stream>>>(W_d1, b_d1, doc, docterm);

  // R = tanh(enc @ W_r^T + b_r)  [512][400]
  gemm_f32<<<dim3(7, 8), 256, 0, stream>>>(enc, 800, W_r, 800, b_r,
                                           Rbuf, 400, 512, 400, 800, 1);
  // Q = R @ W_d1[:,800:1200]^T  [512][100]
  gemm_f32<<<dim3(2, 8), 256, 0, stream>>>(Rbuf, 400, W_d1 + 800, 1600, nullptr,
                                           Qbuf, 100, 512, 100, 400, 0);
  // pre1 = enc @ W_d1[:, :800]^T + docterm  [512][100]
  gemm_f32<<<dim3(2, 8), 256, 0, stream>>>(enc, 800, W_d1, 1600, docterm,
                                           pre1, 100, 512, 100, 800, 0);

  decoder_kernel<<<1, 64, 0, stream>>>(pre1, Qbuf, W_d2, b_d2, nos,
                                       (float*)d_out);
}

// Round 4
// 2476.263 us; speedup vs baseline: 1.6628x; 1.0247x over previous
//
#include <hip/hip_runtime.h>
#include <math.h>

// Problem dims
#define S_N   512
#define WL_N  100
#define E_N   200
#define OC_N  50
#define H_N   400

// ---------------------------------------------------------------------------
// K1: pooled[s][400] = conv_b + (1/L) * sum_{t<L} conv(emb[x])  via prefix sums
// ---------------------------------------------------------------------------
__global__ __launch_bounds__(256, 1)
void pooled_kernel(const int* __restrict__ x, const float* __restrict__ emb,
                   const float* __restrict__ cw0, const float* __restrict__ cw1,
                   const float* __restrict__ cw2, const float* __restrict__ cw3,
                   const float* __restrict__ cw4, const float* __restrict__ cw5,
                   const float* __restrict__ cw6, const float* __restrict__ cw7,
                   const float* __restrict__ conv_b, float* __restrict__ pooled)
{
  const int s = blockIdx.x;
  const int tid = threadIdx.x;
  __shared__ int xr[WL_N];
  __shared__ int Lsh;
  __shared__ float Apart[E_N][17];  // Ssum[e][d+7], d in [-7,7]
  __shared__ float Bpart[E_N][9];   // P[e][d], d in 1..7
  if (tid < WL_N) xr[tid] = x[s * WL_N + tid];
  __syncthreads();
  if (tid == 0) {
    int L = 0;
    for (int t = 0; t < WL_N; ++t) L += (xr[t] != 0) ? 1 : 0;
    Lsh = L;
  }
  __syncthreads();
  const int L = Lsh;  // lengths in [20,100]
  if (tid < E_N) {
    const int e = tid;
    float acc = 0.f;
    for (int t = 0; t < WL_N; ++t) {
      acc += emb[(size_t)xr[t] * E_N + e];
      int m = t + 1;
      if (m <= 7) Bpart[e][m] = acc;                 // P[m], m=1..7
      int rel = m - (L - 7);
      if (rel >= 0 && rel < 15) Apart[e][rel] = acc; // P[L-7+rel]
    }
    const float accF = acc;  // P[100]
    #pragma unroll
    for (int dd = 0; dd < 15; ++dd) {
      int m = L - 7 + dd;
      float A = (m > WL_N) ? accF : Apart[e][dd];
      int d = dd - 7;
      float B = (d > 0) ? Bpart[e][d] : 0.f;
      Apart[e][dd] = A - B;  // sum_{t<L} in[e][t+d], zero-padded
    }
  }
  __syncthreads();
  const float invL = 1.f / (float)L;
  const float* cw[8] = {cw0, cw1, cw2, cw3, cw4, cw5, cw6, cw7};
  for (int c = tid; c < 8 * OC_N; c += 256) {
    int K = c / OC_N, oc = c % OC_N;
    int width = 2 * K + 1;
    const float* w = cw[K] + (size_t)oc * E_N * width;
    float acc = 0.f;
    for (int e = 0; e < E_N; ++e) {
      const float* wr = w + e * width;
      const float* sp = &Apart[e][7 - K];
      for (int k = 0; k < width; ++k) acc += wr[k] * sp[k];
    }
    pooled[(size_t)s * 400 + c] = conv_b[K * OC_N + oc] + acc * invL;
  }
}

// ---------------------------------------------------------------------------
// K2: merged gi GEMM: gi[512][2400] = pooled @ [w_ih_f; w_ih_b]^T + biases
// 64x64 tiles, per-row f/b select. grid (38, 8).
// ---------------------------------------------------------------------------
__global__ __launch_bounds__(256, 2)
void gemm_gi(const float* __restrict__ A,   // pooled [512][400]
             const float* __restrict__ wf, const float* __restrict__ bf,
             const float* __restrict__ wb, const float* __restrict__ bb,
             float* __restrict__ C)         // gi [512][2400]
{
  __shared__ float As[16][65];
  __shared__ float Bs[16][65];
  const int bm = blockIdx.y * 64, bn = blockIdx.x * 64;
  const int tid = threadIdx.x;
  const int tr = (tid / 16) * 4, tc = (tid % 16) * 4;
  float acc[4][4] = {};
  for (int k0 = 0; k0 < 400; k0 += 16) {
    for (int l = tid; l < 64 * 16; l += 256) {
      int r = l / 16, c = l % 16;
      As[c][r] = A[(size_t)(bm + r) * 400 + k0 + c];
    }
    for (int l = tid; l < 64 * 16; l += 256) {
      int r = l / 16, c = l % 16;
      int gcol = bn + r;
      float v = 0.f;
      if (gcol < 1200)      v = wf[(size_t)gcol * 400 + k0 + c];
      else if (gcol < 2400) v = wb[(size_t)(gcol - 1200) * 400 + k0 + c];
      Bs[c][r] = v;
    }
    __syncthreads();
    #pragma unroll
    for (int kk = 0; kk < 16; ++kk) {
      float a[4], b[4];
      #pragma unroll
      for (int u = 0; u < 4; ++u) { a[u] = As[kk][tr + u]; b[u] = Bs[kk][tc + u]; }
      #pragma unroll
      for (int u = 0; u < 4; ++u)
        #pragma unroll
        for (int v = 0; v < 4; ++v) acc[u][v] += a[u] * b[v];
    }
    __syncthreads();
  }
  for (int u = 0; u < 4; ++u) {
    int r = bm + tr + u;
    for (int v = 0; v < 4; ++v) {
      int c = bn + tc + v; if (c >= 2400) continue;
      float bias = (c < 1200) ? bf[c] : bb[c - 1200];
      C[(size_t)r * 2400 + c] = acc[u][v] + bias;
    }
  }
}

// ---------------------------------------------------------------------------
// 32x32-tile GEMM: C[M,N] = A[M,K] @ B[N,K]^T + bias[N] (optional tanh).
// TAG distinguishes call sites in the profiler.
// ---------------------------------------------------------------------------
template<int TAG>
__global__ __launch_bounds__(256, 4)
void gemm32(const float* __restrict__ A, int lda,
            const float* __restrict__ Bw, int ldb,
            const float* __restrict__ bias,
            float* __restrict__ C, int ldc,
            int M, int N, int K, int act)
{
  __shared__ float As[32][33];
  __shared__ float Bs[32][33];
  const int bm = blockIdx.y * 32, bn = blockIdx.x * 32;
  const int tid = threadIdx.x;
  const int tr = (tid >> 4) * 2, tc = (tid & 15) * 2;
  float acc[2][2] = {};
  for (int k0 = 0; k0 < K; k0 += 32) {
    #pragma unroll
    for (int p = 0; p < 4; ++p) {
      int l = tid + p * 256;
      int r = l >> 5, c = l & 31;
      As[c][r] = (bm + r < M) ? A[(size_t)(bm + r) * lda + k0 + c] : 0.f;
      Bs[c][r] = (bn + r < N) ? Bw[(size_t)(bn + r) * ldb + k0 + c] : 0.f;
    }
    __syncthreads();
    #pragma unroll
    for (int kk = 0; kk < 32; ++kk) {
      float a0 = As[kk][tr], a1 = As[kk][tr + 1];
      float b0 = Bs[kk][tc], b1 = Bs[kk][tc + 1];
      acc[0][0] += a0 * b0; acc[0][1] += a0 * b1;
      acc[1][0] += a1 * b0; acc[1][1] += a1 * b1;
    }
    __syncthreads();
  }
  #pragma unroll
  for (int u = 0; u < 2; ++u) {
    int r = bm + tr + u; if (r >= M) continue;
    #pragma unroll
    for (int v = 0; v < 2; ++v) {
      int c = bn + tc + v; if (c >= N) continue;
      float xv = acc[u][v] + (bias ? bias[c] : 0.f);
      if (act == 1) xv = tanhf(xv);
      C[(size_t)r * ldc + c] = xv;
    }
  }
}

// ---------------------------------------------------------------------------
// K3: bidirectional GRU scan, 25 blocks x 256 threads per direction.
// h published as (tag<<32 | f32) via relaxed agent-scope u64 stores (LLC).
// Sentinel gating: producer tid0 fires a compact per-block sentinel word;
// readers' wave 0 polls 25 sentinels (2 lines) instead of 400 words, then the
// block bulk-loads + verifies tags (wave-local retry). Parity double-buffer;
// sent[b]>=t+1 implies block b consumed h_t, so slot reuse is race-free.
// ---------------------------------------------------------------------------
#define GRU_NB 25
#define GRU_CHUNK 16
__global__ __launch_bounds__(256, 1)
void gru_scan_kernel(const float* __restrict__ gi,  // [512][2400] f|b
                     const float* __restrict__ whh_f, const float* __restrict__ bhh_f,
                     const float* __restrict__ whh_b, const float* __restrict__ bhh_b,
                     float* __restrict__ enc,                  // [512][800]
                     unsigned long long* __restrict__ hbuf,    // [2 dirs][2][400]
                     unsigned int* __restrict__ sent)          // [2 dirs][32]
{
  const int tid = threadIdx.x;
  const int dir = blockIdx.x / GRU_NB;
  const int b   = blockIdx.x % GRU_NB;
  const float* whh = dir ? whh_b : whh_f;
  const float* bhh = dir ? bhh_b : bhh_f;
  unsigned long long* hb = hbuf + (size_t)dir * 800;
  unsigned int* st = sent + dir * 32;
  const int i0 = b * GRU_CHUNK;

  __shared__ float wl[48][400];   // 76.8 KB
  __shared__ float hs[400];

  for (int l = tid; l < 48 * 400; l += 256) {
    int lr = l / 400, c = l % 400;
    int g = lr / GRU_CHUNK, ii = lr % GRU_CHUNK;
    wl[lr][c] = whh[(size_t)(g * 400 + i0 + ii) * 400 + c];
  }

  const int i  = tid >> 4;   // 0..15: which h-index in our chunk
  const int cc = tid & 15;   // 0..15: column chunk
  const int c0 = cc * 25;

  float blr = 0.f, blz = 0.f, bln = 0.f;
  if (cc == 0) {
    blr = bhh[i0 + i];
    blz = bhh[400 + i0 + i];
    bln = bhh[800 + i0 + i];
  }
  __syncthreads();

  const int idx0 = tid;        // always < 400
  const int idx1 = tid + 256;  // valid if < 400

  for (int t = 0; t < 512; ++t) {
    const int t_in = dir ? (511 - t) : t;
    // prefetch gi row for this step (independent of sync)
    float gir = 0.f, giz = 0.f, gin = 0.f;
    if (cc == 0) {
      const float* girow = gi + (size_t)t_in * 2400 + dir * 1200 + i0 + i;
      gir = girow[0]; giz = girow[400]; gin = girow[800];
    }
    // sentinel gate: wave 0 polls 25 compact words
    if (t > 0 && tid < 64) {
      const unsigned want = (unsigned)t;
      for (;;) {
        unsigned sv = (tid < GRU_NB)
            ? __hip_atomic_load(st + tid, __ATOMIC_RELAXED, __HIP_MEMORY_SCOPE_AGENT)
            : want;
        if (__all(sv >= want)) break;
        __builtin_amdgcn_s_sleep(1);
      }
    }
    __syncthreads();
    // bulk tagged load + wave-local verify
    {
      const unsigned long long* src = hb + (t & 1) * 400;
      const unsigned want = (unsigned)t;
      unsigned long long u0, u1 = 0;
      for (;;) {
        bool ok;
        u0 = __hip_atomic_load(src + idx0, __ATOMIC_RELAXED, __HIP_MEMORY_SCOPE_AGENT);
        ok = ((unsigned)(u0 >> 32) == want);
        if (idx1 < 400) {
          u1 = __hip_atomic_load(src + idx1, __ATOMIC_RELAXED, __HIP_MEMORY_SCOPE_AGENT);
          ok &= ((unsigned)(u1 >> 32) == want);
        }
        if (__all(ok)) break;
        __builtin_amdgcn_s_sleep(1);
      }
      hs[idx0] = __uint_as_float((unsigned)u0);
      if (idx1 < 400) hs[idx1] = __uint_as_float((unsigned)u1);
    }
    __syncthreads();   // hs ready

    // 3 gate partial dots over our 25-column chunk
    float a0 = 0.f, a1 = 0.f, a2 = 0.f;
    #pragma unroll
    for (int j = 0; j < 25; ++j) {
      float hv = hs[c0 + j];
      a0 += wl[i][c0 + j] * hv;
      a1 += wl[16 + i][c0 + j] * hv;
      a2 += wl[32 + i][c0 + j] * hv;
    }
    #pragma unroll
    for (int m = 1; m <= 8; m <<= 1) {
      a0 += __shfl_xor(a0, m);
      a1 += __shfl_xor(a1, m);
      a2 += __shfl_xor(a2, m);
    }
    if (cc == 0) {
      float r = 1.f / (1.f + expf(-(gir + a0 + blr)));
      float z = 1.f / (1.f + expf(-(giz + a1 + blz)));
      float n = tanhf(gin + r * (a2 + bln));
      float hprev = hs[i0 + i];
      float hn = (1.f - z) * n + z * hprev;
      unsigned long long pk =
          ((unsigned long long)(unsigned)(t + 1) << 32) | (unsigned long long)__float_as_uint(hn);
      __hip_atomic_store(hb + ((t + 1) & 1) * 400 + i0 + i, pk,
                         __ATOMIC_RELAXED, __HIP_MEMORY_SCOPE_AGENT);
      enc[(size_t)t_in * 800 + dir * 400 + i0 + i] = hn;
    }
    if (tid == 0) {
      // fire-and-forget sentinel (same lane as its h store -> issues after it;
      // readers re-verify data tags, so visibility skew is harmless)
      __hip_atomic_store(st + b, (unsigned)(t + 1),
                         __ATOMIC_RELAXED, __HIP_MEMORY_SCOPE_AGENT);
    }
    // no trailing barrier needed: a wave overwrites hs only after its bulk
    // verify for t+1 succeeds, which requires all blocks to have published t+1
    // (hence finished reading hs data of step t).
  }
}

// ---------------------------------------------------------------------------
// K4a: column mean of enc -> mean[800]. 50 blocks x 256 thr (16 cols each).
// ---------------------------------------------------------------------------
__global__ void mean_kernel(const float* __restrict__ enc, float* __restrict__ mean)
{
  __shared__ float part[16][17];
  const int c = threadIdx.x & 15, rch = threadIdx.x >> 4;
  const int col = blockIdx.x * 16 + c;
  float s = 0.f;
  for (int r = rch; r < 512; r += 16) s += enc[(size_t)r * 800 + col];
  part[rch][c] = s;
  __syncthreads();
  if (threadIdx.x < 16) {
    float tt = 0.f;
    #pragma unroll
    for (int k = 0; k < 16; ++k) tt += part[k][threadIdx.x];
    mean[blockIdx.x * 16 + threadIdx.x] = tt * (1.f / 512.f);
  }
}

// K4b: doc[r] = tanh(W_doc[r]·mean + b_doc[r]); one block (64 lanes) per row
__global__ void doc_kernel(const float* __restrict__ W_doc, const float* __restrict__ b_doc,
                           const float* __restrict__ mean, float* __restrict__ doc)
{
  int r = blockIdx.x, lane = threadIdx.x;
  float s = 0.f;
  for (int k = lane; k < 800; k += 64) s += W_doc[(size_t)r * 800 + k] * mean[k];
  s += __shfl_xor(s, 1);  s += __shfl_xor(s, 2);  s += __shfl_xor(s, 4);
  s += __shfl_xor(s, 8);  s += __shfl_xor(s, 16); s += __shfl_xor(s, 32);
  if (lane == 0) doc[r] = tanhf(s + b_doc[r]);
}

// K4c: docterm[r] = W_d1[r,1200:1600]·doc + b_d1[r]
__global__ void docterm_kernel(const float* __restrict__ W_d1, const float* __restrict__ b_d1,
                               const float* __restrict__ doc, float* __restrict__ docterm)
{
  int r = blockIdx.x, lane = threadIdx.x;
  float s = 0.f;
  for (int k = lane; k < 400; k += 64) s += W_d1[(size_t)r * 1600 + 1200 + k] * doc[k];
  s += __shfl_xor(s, 1);  s += __shfl_xor(s, 2);  s += __shfl_xor(s, 4);
  s += __shfl_xor(s, 8);  s += __shfl_xor(s, 16); s += __shfl_xor(s, 32);
  if (lane == 0) docterm[r] = s + b_d1[r];
}

// ---------------------------------------------------------------------------
// K6: decoder via parallel segment passes. Between selections q = W_mid@g is
// constant, so all logits of a segment are computable in parallel; at most
// num_of_sent selections (3 here) -> <=5 passes. 1 block x 1024 threads,
// row = tid>>1, half = tid&1 (50 features each).
// ---------------------------------------------------------------------------
__global__ __launch_bounds__(1024, 1)
void decoder_kernel(const float* __restrict__ pre1,  // [512][100]
                    const float* __restrict__ Qb,    // [512][100]
                    const float* __restrict__ W_d2,  // [100]
                    const float* __restrict__ b_d2,  // [1]
                    const int* __restrict__ nos_p,
                    float* __restrict__ out)         // [513]: logp, sels
{
  const int tid = threadIdx.x;
  const int row = tid >> 1;
  const int half = tid & 1;
  __shared__ float q[100];
  __shared__ float w2s[100];
  __shared__ int   selfl[512];
  __shared__ int   firstpos;
  __shared__ float red[16];
  if (tid < 100) { q[tid] = 0.f; w2s[tid] = W_d2[tid]; }
  if (tid < 512) selfl[tid] = 0;
  float pr[50];
  #pragma unroll
  for (int k = 0; k < 50; ++k) pr[k] = pre1[(size_t)row * 100 + half * 50 + k];
  const float bd2 = b_d2[0];
  const int nos = nos_p[0];
  int count = 0, seg = 0;
  float logp_part = 0.f;
  __syncthreads();

  for (int pass = 0; pass < 600 && seg < 512; ++pass) {
    const bool allowed = (nos <= 0) || (count < nos);
    if (tid == 0) firstpos = 512;
    float acc = 0.f;
    #pragma unroll
    for (int k = 0; k < 50; ++k)
      acc += w2s[half * 50 + k] * tanhf(pr[k] + q[half * 50 + k]);
    acc += __shfl_xor(acc, 1);     // combine the two halves of this row
    const float sv = acc + bd2;    // logit s'; p>0.5 <=> sv>0
    __syncthreads();               // firstpos reset visible; q reads done
    if (allowed && half == 0 && row >= seg && sv > 0.f)
      atomicMin(&firstpos, row);
    __syncthreads();
    const int fp = allowed ? firstpos : 512;
    const int lim = (fp < 512) ? fp : 511;
    if (half == 0 && row >= seg && row <= lim) {
      float p = 1.f / (1.f + expf(-sv));
      float term = (row == fp) ? p : (1.f - p);
      logp_part += logf(term * 0.99999f + 5e-6f);
      if (row == fp) selfl[row] = 1;
    }
    if (fp < 512) {
      if (tid < 100) q[tid] += Qb[(size_t)fp * 100 + tid];
      count += 1;
      seg = fp + 1;
    } else {
      seg = 512;
    }
    __syncthreads();               // q update complete before next pass
  }

  float v = logp_part;
  v += __shfl_xor(v, 1);  v += __shfl_xor(v, 2);  v += __shfl_xor(v, 4);
  v += __shfl_xor(v, 8);  v += __shfl_xor(v, 16); v += __shfl_xor(v, 32);
  if ((tid & 63) == 0) red[tid >> 6] = v;
  __syncthreads();
  if (tid == 0) {
    float s = 0.f;
    #pragma unroll
    for (int w = 0; w < 16; ++w) s += red[w];
    out[0] = s;
  }
  if (half == 0) out[1 + row] = (float)selfl[row];
}

// ---------------------------------------------------------------------------
// Launcher
// ---------------------------------------------------------------------------
extern "C" void kernel_launch(void* const* d_in, const int* in_sizes, int n_in,
                              void* d_out, int out_size, void* d_ws, size_t ws_size,
                              hipStream_t stream) {
  const int*   x      = (const int*)  d_in[0];
  const int*   nos    = (const int*)  d_in[1];
  const float* emb    = (const float*)d_in[2];
  const float* cw[8];
  for (int k = 0; k < 8; ++k) cw[k] = (const float*)d_in[3 + k];
  const float* conv_b = (const float*)d_in[11];
  const float* w_ih_f = (const float*)d_in[12];
  const float* w_hh_f = (const float*)d_in[13];
  const float* b_ih_f = (const float*)d_in[14];
  const float* b_hh_f = (const float*)d_in[15];
  const float* w_ih_b = (const float*)d_in[16];
  const float* w_hh_b = (const float*)d_in[17];
  const float* b_ih_b = (const float*)d_in[18];
  const float* b_hh_b = (const float*)d_in[19];
  const float* W_doc  = (const float*)d_in[20];
  const float* b_doc  = (const float*)d_in[21];
  const float* W_d1   = (const float*)d_in[22];
  const float* b_d1   = (const float*)d_in[23];
  const float* W_d2   = (const float*)d_in[24];
  const float* b_d2   = (const float*)d_in[25];
  const float* W_r    = (const float*)d_in[26];
  const float* b_r    = (const float*)d_in[27];

  float* ws = (float*)d_ws;
  const size_t OFF_POOLED  = 0;         // 512*400 (reused: hbuf+sent after gi gemm)
  const size_t OFF_GI      = 204800;    // 512*2400 (reused as Qbuf later)
  const size_t OFF_ENC     = 1433600;   // 512*800
  const size_t OFF_R       = 1843200;   // 512*400
  const size_t OFF_PRE1    = 2048000;   // 512*100
  const size_t OFF_MEAN    = 2099200;   // 800
  const size_t OFF_DOC     = 2100000;   // 400
  const size_t OFF_DOCTERM = 2100400;   // 100 (+pad)
  float* pooled  = ws + OFF_POOLED;
  float* gi      = ws + OFF_GI;
  float* enc     = ws + OFF_ENC;
  float* Rbuf    = ws + OFF_R;
  float* pre1    = ws + OFF_PRE1;
  float* mean    = ws + OFF_MEAN;
  float* doc     = ws + OFF_DOC;
  float* docterm = ws + OFF_DOCTERM;
  float* Qbuf    = ws + OFF_GI;     // gi dead after GRU; reuse for Q
  // hbuf + sent alias the pooled region (dead after the gi GEMM):
  // hbuf 2*2*400 u64 = 25.6 KB, sent 2*32 u32 = 256 B
  unsigned long long* hbuf = (unsigned long long*)(ws + OFF_POOLED);
  unsigned int* sentp = (unsigned int*)(hbuf + 1600);

  pooled_kernel<<<512, 256, 0, stream>>>(x, emb, cw[0], cw[1], cw[2], cw[3],
                                         cw[4], cw[5], cw[6], cw[7], conv_b, pooled);

  // gi = pooled @ [w_ih_f; w_ih_b]^T + bias  -> [512][2400]  (one launch)
  gemm_gi<<<dim3(38, 8), 256, 0, stream>>>(pooled, w_ih_f, b_ih_f, w_ih_b, b_ih_b, gi);

  // zero tagged h buffers + sentinels (pooled region is dead now)
  hipMemsetAsync(hbuf, 0, 1600 * sizeof(unsigned long long) + 64 * sizeof(unsigned int),
                 stream);

  gru_scan_kernel<<<2 * GRU_NB, 256, 0, stream>>>(gi, w_hh_f, b_hh_f, w_hh_b, b_hh_b,
                                                  enc, hbuf, sentp);

  mean_kernel<<<50, 256, 0, stream>>>(enc, mean);
  doc_kernel<<<400, 64, 0, stream>>>(W_doc, b_doc, mean, doc);
  docterm_kernel<<<100, 64, 0, stream>>>(W_d1, b_d1, doc, docterm);

  // R = tanh(enc @ W_r^T + b_r)  [512][400]
  gemm32<1><<<dim3(13, 16), 256, 0, stream>>>(enc, 800, W_r, 800, b_r,
                                              Rbuf, 400, 512, 400, 800, 1);
  // Q = R @ W_d1[:,800:1200]^T  [512][100]
  gemm32<2><<<dim3(4, 16), 256, 0, stream>>>(Rbuf, 400, W_d1 + 800, 1600, nullptr,
                                             Qbuf, 100, 512, 100, 400, 0);
  // pre1 = enc @ W_d1[:, :800]^T + docterm  [512][100]
  gemm32<3><<<dim3(4, 16), 256, 0, stream>>>(enc, 800, W_d1, 1600, docterm,
                                             pre1, 100, 512, 100, 800, 0);

  decoder_kernel<<<1, 1024, 0, stream>>>(pre1, Qbuf, W_d2, b_d2, nos,
                                         (float*)d_out);
}

// Round 6
// 2158.051 us; speedup vs baseline: 1.9080x; 1.1475x over previous
//
#include <hip/hip_runtime.h>
#include <math.h>

// Problem dims
#define S_N   512
#define WL_N  100
#define E_N   200
#define OC_N  50
#define H_N   400

// ---------------------------------------------------------------------------
// K1: pooled[s][400] = conv_b + (1/L) * sum_{t<L} conv(emb[x])  via prefix sums
// Conv stage: one (K,oc) pair per WAVE -> coalesced weight reads.
// ---------------------------------------------------------------------------
template<int K>
__device__ inline float conv_dot(const float* __restrict__ wbase,
                                 const float (*Ap)[17], int lane)
{
  constexpr int W = 2 * K + 1;
  constexpr int n = E_N * W;
  float acc = 0.f;
  for (int idx = lane; idx < n; idx += 64) {
    int e = idx / W;
    int k = idx - e * W;
    acc += wbase[idx] * Ap[e][7 - K + k];
  }
  return acc;
}

__global__ __launch_bounds__(256, 1)
void pooled_kernel(const int* __restrict__ x, const float* __restrict__ emb,
                   const float* __restrict__ cw0, const float* __restrict__ cw1,
                   const float* __restrict__ cw2, const float* __restrict__ cw3,
                   const float* __restrict__ cw4, const float* __restrict__ cw5,
                   const float* __restrict__ cw6, const float* __restrict__ cw7,
                   const float* __restrict__ conv_b, float* __restrict__ pooled)
{
  const int s = blockIdx.x;
  const int tid = threadIdx.x;
  __shared__ int xr[WL_N];
  __shared__ int Lsh;
  __shared__ float Apart[E_N][17];  // windowed sums, d+7 in [0,14]
  __shared__ float Bpart[E_N][9];   // prefix P[m], m=1..7
  if (tid < WL_N) xr[tid] = x[s * WL_N + tid];
  __syncthreads();
  if (tid == 0) {
    int L = 0;
    for (int t = 0; t < WL_N; ++t) L += (xr[t] != 0) ? 1 : 0;
    Lsh = L;
  }
  __syncthreads();
  const int L = Lsh;  // lengths in [20,100]
  if (tid < E_N) {
    const int e = tid;
    float acc = 0.f;
    for (int t = 0; t < WL_N; ++t) {
      acc += emb[(size_t)xr[t] * E_N + e];
      int m = t + 1;
      if (m <= 7) Bpart[e][m] = acc;                 // P[m], m=1..7
      int rel = m - (L - 7);
      if (rel >= 0 && rel < 15) Apart[e][rel] = acc; // P[L-7+rel]
    }
    const float accF = acc;  // P[100]
    #pragma unroll
    for (int dd = 0; dd < 15; ++dd) {
      int m = L - 7 + dd;
      float A = (m > WL_N) ? accF : Apart[e][dd];
      int d = dd - 7;
      float B = (d > 0) ? Bpart[e][d] : 0.f;
      Apart[e][dd] = A - B;  // sum_{t<L} in[e][t+d], zero-padded
    }
  }
  __syncthreads();
  const float invL = 1.f / (float)L;
  const int wv = tid >> 6, lane = tid & 63;
  for (int p = wv; p < 400; p += 4) {
    const int K = p / 50, oc = p % 50;
    float acc = 0.f;
    switch (K) {
      case 0: acc = conv_dot<0>(cw0 + (size_t)oc * 200,  Apart, lane); break;
      case 1: acc = conv_dot<1>(cw1 + (size_t)oc * 600,  Apart, lane); break;
      case 2: acc = conv_dot<2>(cw2 + (size_t)oc * 1000, Apart, lane); break;
      case 3: acc = conv_dot<3>(cw3 + (size_t)oc * 1400, Apart, lane); break;
      case 4: acc = conv_dot<4>(cw4 + (size_t)oc * 1800, Apart, lane); break;
      case 5: acc = conv_dot<5>(cw5 + (size_t)oc * 2200, Apart, lane); break;
      case 6: acc = conv_dot<6>(cw6 + (size_t)oc * 2600, Apart, lane); break;
      case 7: acc = conv_dot<7>(cw7 + (size_t)oc * 3000, Apart, lane); break;
    }
    acc += __shfl_xor(acc, 1);  acc += __shfl_xor(acc, 2);
    acc += __shfl_xor(acc, 4);  acc += __shfl_xor(acc, 8);
    acc += __shfl_xor(acc, 16); acc += __shfl_xor(acc, 32);
    if (lane == 0)
      pooled[(size_t)s * 400 + p] = conv_b[p] + acc * invL;
  }
}

// ---------------------------------------------------------------------------
// K2: merged gi GEMM: gi[512][2400] = pooled @ [w_ih_f; w_ih_b]^T + biases
// ---------------------------------------------------------------------------
__global__ __launch_bounds__(256, 2)
void gemm_gi(const float* __restrict__ A,   // pooled [512][400]
             const float* __restrict__ wf, const float* __restrict__ bf,
             const float* __restrict__ wb, const float* __restrict__ bb,
             float* __restrict__ C)         // gi [512][2400]
{
  __shared__ float As[16][65];
  __shared__ float Bs[16][65];
  const int bm = blockIdx.y * 64, bn = blockIdx.x * 64;
  const int tid = threadIdx.x;
  const int tr = (tid / 16) * 4, tc = (tid % 16) * 4;
  float acc[4][4] = {};
  for (int k0 = 0; k0 < 400; k0 += 16) {
    for (int l = tid; l < 64 * 16; l += 256) {
      int r = l / 16, c = l % 16;
      As[c][r] = A[(size_t)(bm + r) * 400 + k0 + c];
    }
    for (int l = tid; l < 64 * 16; l += 256) {
      int r = l / 16, c = l % 16;
      int gcol = bn + r;
      float v = 0.f;
      if (gcol < 1200)      v = wf[(size_t)gcol * 400 + k0 + c];
      else if (gcol < 2400) v = wb[(size_t)(gcol - 1200) * 400 + k0 + c];
      Bs[c][r] = v;
    }
    __syncthreads();
    #pragma unroll
    for (int kk = 0; kk < 16; ++kk) {
      float a[4], b[4];
      #pragma unroll
      for (int u = 0; u < 4; ++u) { a[u] = As[kk][tr + u]; b[u] = Bs[kk][tc + u]; }
      #pragma unroll
      for (int u = 0; u < 4; ++u)
        #pragma unroll
        for (int v = 0; v < 4; ++v) acc[u][v] += a[u] * b[v];
    }
    __syncthreads();
  }
  for (int u = 0; u < 4; ++u) {
    int r = bm + tr + u;
    for (int v = 0; v < 4; ++v) {
      int c = bn + tc + v; if (c >= 2400) continue;
      float bias = (c < 1200) ? bf[c] : bb[c - 1200];
      C[(size_t)r * 2400 + c] = acc[u][v] + bias;
    }
  }
}

// ---------------------------------------------------------------------------
// 32x32-tile GEMM: C[M,N] = A[M,K] @ B[N,K]^T + bias[N] (optional tanh).
// ---------------------------------------------------------------------------
template<int TAG>
__global__ __launch_bounds__(256, 4)
void gemm32(const float* __restrict__ A, int lda,
            const float* __restrict__ Bw, int ldb,
            const float* __restrict__ bias,
            float* __restrict__ C, int ldc,
            int M, int N, int K, int act)
{
  __shared__ float As[32][33];
  __shared__ float Bs[32][33];
  const int bm = blockIdx.y * 32, bn = blockIdx.x * 32;
  const int tid = threadIdx.x;
  const int tr = (tid >> 4) * 2, tc = (tid & 15) * 2;
  float acc[2][2] = {};
  for (int k0 = 0; k0 < K; k0 += 32) {
    #pragma unroll
    for (int p = 0; p < 4; ++p) {
      int l = tid + p * 256;
      int r = l >> 5, c = l & 31;
      As[c][r] = (bm + r < M) ? A[(size_t)(bm + r) * lda + k0 + c] : 0.f;
      Bs[c][r] = (bn + r < N) ? Bw[(size_t)(bn + r) * ldb + k0 + c] : 0.f;
    }
    __syncthreads();
    #pragma unroll
    for (int kk = 0; kk < 32; ++kk) {
      float a0 = As[kk][tr], a1 = As[kk][tr + 1];
      float b0 = Bs[kk][tc], b1 = Bs[kk][tc + 1];
      acc[0][0] += a0 * b0; acc[0][1] += a0 * b1;
      acc[1][0] += a1 * b0; acc[1][1] += a1 * b1;
    }
    __syncthreads();
  }
  #pragma unroll
  for (int u = 0; u < 2; ++u) {
    int r = bm + tr + u; if (r >= M) continue;
    #pragma unroll
    for (int v = 0; v < 2; ++v) {
      int c = bn + tc + v; if (c >= N) continue;
      float xv = acc[u][v] + (bias ? bias[c] : 0.f);
      if (act == 1) xv = tanhf(xv);
      C[(size_t)r * ldc + c] = xv;
    }
  }
}

// ---------------------------------------------------------------------------
// K3: bidirectional GRU scan, 25 blocks x 256 threads per direction.
// PROVEN round-3 protocol (1141us): h published as (tag<<32 | f32) via relaxed
// agent-scope 64-bit atomic intrinsics (compiler emits correct cache flags).
// Readers poll the tagged data itself. Parity double-buffer; exact-tag check
// (stale reads can only show t-2, never t+-1). One barrier per step.
// ---------------------------------------------------------------------------
#define GRU_NB 25
#define GRU_CHUNK 16
__global__ __launch_bounds__(256, 1)
void gru_scan_kernel(const float* __restrict__ gi,  // [512][2400] f|b
                     const float* __restrict__ whh_f, const float* __restrict__ bhh_f,
                     const float* __restrict__ whh_b, const float* __restrict__ bhh_b,
                     float* __restrict__ enc,                  // [512][800]
                     unsigned long long* __restrict__ hbuf)    // [2 dirs][2][400]
{
  const int tid = threadIdx.x;
  const int dir = blockIdx.x / GRU_NB;
  const int b   = blockIdx.x % GRU_NB;
  const float* whh = dir ? whh_b : whh_f;
  const float* bhh = dir ? bhh_b : bhh_f;
  unsigned long long* hb = hbuf + (size_t)dir * 800;
  const int i0 = b * GRU_CHUNK;

  __shared__ float wl[48][400];   // 76.8 KB
  __shared__ float hs[400];

  for (int l = tid; l < 48 * 400; l += 256) {
    int lr = l / 400, c = l % 400;
    int g = lr / GRU_CHUNK, ii = lr % GRU_CHUNK;
    wl[lr][c] = whh[(size_t)(g * 400 + i0 + ii) * 400 + c];
  }

  const int i  = tid >> 4;   // 0..15: which h-index in our chunk
  const int cc = tid & 15;   // 0..15: column chunk
  const int c0 = cc * 25;

  float blr = 0.f, blz = 0.f, bln = 0.f;
  if (cc == 0) {
    blr = bhh[i0 + i];
    blz = bhh[400 + i0 + i];
    bln = bhh[800 + i0 + i];
  }
  __syncthreads();

  const int idx0 = tid;        // always < 400
  const int idx1 = tid + 256;  // valid if < 400

  for (int t = 0; t < 512; ++t) {
    const int t_in = dir ? (511 - t) : t;
    // prefetch gi row for this step (independent of sync)
    float gir = 0.f, giz = 0.f, gin = 0.f;
    if (cc == 0) {
      const float* girow = gi + (size_t)t_in * 2400 + dir * 1200 + i0 + i;
      gir = girow[0]; giz = girow[400]; gin = girow[800];
    }
    // poll tagged h of step t (slot t&1); every thread covers <=2 entries
    {
      const unsigned long long* src = hb + (t & 1) * 400;
      const unsigned want = (unsigned)t;
      unsigned long long u0, u1 = 0;
      for (;;) {
        bool ok = true;
        u0 = __hip_atomic_load(src + idx0, __ATOMIC_RELAXED, __HIP_MEMORY_SCOPE_AGENT);
        ok &= ((unsigned)(u0 >> 32) == want);
        if (idx1 < 400) {
          u1 = __hip_atomic_load(src + idx1, __ATOMIC_RELAXED, __HIP_MEMORY_SCOPE_AGENT);
          ok &= ((unsigned)(u1 >> 32) == want);
        }
        if (__all(ok)) break;
        __builtin_amdgcn_s_sleep(1);
      }
      hs[idx0] = __uint_as_float((unsigned)u0);
      if (idx1 < 400) hs[idx1] = __uint_as_float((unsigned)u1);
    }
    __syncthreads();   // hs ready (the ONLY barrier per step)

    // 3 gate partial dots over our 25-column chunk
    float a0 = 0.f, a1 = 0.f, a2 = 0.f;
    #pragma unroll
    for (int j = 0; j < 25; ++j) {
      float hv = hs[c0 + j];
      a0 += wl[i][c0 + j] * hv;
      a1 += wl[16 + i][c0 + j] * hv;
      a2 += wl[32 + i][c0 + j] * hv;
    }
    #pragma unroll
    for (int m = 1; m <= 8; m <<= 1) {
      a0 += __shfl_xor(a0, m);
      a1 += __shfl_xor(a1, m);
      a2 += __shfl_xor(a2, m);
    }
    if (cc == 0) {
      float r = 1.f / (1.f + expf(-(gir + a0 + blr)));
      float z = 1.f / (1.f + expf(-(giz + a1 + blz)));
      float n = tanhf(gin + r * (a2 + bln));
      float hprev = hs[i0 + i];
      float hn = (1.f - z) * n + z * hprev;
      unsigned long long pk =
          ((unsigned long long)(unsigned)(t + 1) << 32) | (unsigned long long)__float_as_uint(hn);
      __hip_atomic_store(hb + ((t + 1) & 1) * 400 + i0 + i, pk,
                         __ATOMIC_RELAXED, __HIP_MEMORY_SCOPE_AGENT);
      enc[(size_t)t_in * 800 + dir * 400 + i0 + i] = hn;
    }
    // no trailing barrier: slot (t&1) is only overwritten by h(t+2) stores,
    // which require every block to have passed poll(t+1), which requires all
    // waves everywhere (incl. ours) to have finished reading hs of step t.
  }
}

// ---------------------------------------------------------------------------
// K4a: column mean of enc -> mean[800]. 50 blocks x 256 thr (16 cols each).
// ---------------------------------------------------------------------------
__global__ void mean_kernel(const float* __restrict__ enc, float* __restrict__ mean)
{
  __shared__ float part[16][17];
  const int c = threadIdx.x & 15, rch = threadIdx.x >> 4;
  const int col = blockIdx.x * 16 + c;
  float s = 0.f;
  for (int r = rch; r < 512; r += 16) s += enc[(size_t)r * 800 + col];
  part[rch][c] = s;
  __syncthreads();
  if (threadIdx.x < 16) {
    float tt = 0.f;
    #pragma unroll
    for (int k = 0; k < 16; ++k) tt += part[k][threadIdx.x];
    mean[blockIdx.x * 16 + threadIdx.x] = tt * (1.f / 512.f);
  }
}

// K4b: doc[r] = tanh(W_doc[r]·mean + b_doc[r]); one block (64 lanes) per row
__global__ void doc_kernel(const float* __restrict__ W_doc, const float* __restrict__ b_doc,
                           const float* __restrict__ mean, float* __restrict__ doc)
{
  int r = blockIdx.x, lane = threadIdx.x;
  float s = 0.f;
  for (int k = lane; k < 800; k += 64) s += W_doc[(size_t)r * 800 + k] * mean[k];
  s += __shfl_xor(s, 1);  s += __shfl_xor(s, 2);  s += __shfl_xor(s, 4);
  s += __shfl_xor(s, 8);  s += __shfl_xor(s, 16); s += __shfl_xor(s, 32);
  if (lane == 0) doc[r] = tanhf(s + b_doc[r]);
}

// K4c: docterm[r] = W_d1[r,1200:1600]·doc + b_d1[r]
__global__ void docterm_kernel(const float* __restrict__ W_d1, const float* __restrict__ b_d1,
                               const float* __restrict__ doc, float* __restrict__ docterm)
{
  int r = blockIdx.x, lane = threadIdx.x;
  float s = 0.f;
  for (int k = lane; k < 400; k += 64) s += W_d1[(size_t)r * 1600 + 1200 + k] * doc[k];
  s += __shfl_xor(s, 1);  s += __shfl_xor(s, 2);  s += __shfl_xor(s, 4);
  s += __shfl_xor(s, 8);  s += __shfl_xor(s, 16); s += __shfl_xor(s, 32);
  if (lane == 0) docterm[r] = s + b_d1[r];
}

// ---------------------------------------------------------------------------
// K6: decoder via parallel segment passes (q constant between selections;
// <= num_of_sent selections -> few passes). 1 block x 1024 threads.
// ---------------------------------------------------------------------------
__global__ __launch_bounds__(1024, 1)
void decoder_kernel(const float* __restrict__ pre1,  // [512][100]
                    const float* __restrict__ Qb,    // [512][100]
                    const float* __restrict__ W_d2,  // [100]
                    const float* __restrict__ b_d2,  // [1]
                    const int* __restrict__ nos_p,
                    float* __restrict__ out)         // [513]: logp, sels
{
  const int tid = threadIdx.x;
  const int row = tid >> 1;
  const int half = tid & 1;
  __shared__ float q[100];
  __shared__ float w2s[100];
  __shared__ int   selfl[512];
  __shared__ int   firstpos;
  __shared__ float red[16];
  if (tid < 100) { q[tid] = 0.f; w2s[tid] = W_d2[tid]; }
  if (tid < 512) selfl[tid] = 0;
  float pr[50];
  #pragma unroll
  for (int k = 0; k < 50; ++k) pr[k] = pre1[(size_t)row * 100 + half * 50 + k];
  const float bd2 = b_d2[0];
  const int nos = nos_p[0];
  int count = 0, seg = 0;
  float logp_part = 0.f;
  __syncthreads();

  for (int pass = 0; pass < 600 && seg < 512; ++pass) {
    const bool allowed = (nos <= 0) || (count < nos);
    if (tid == 0) firstpos = 512;
    float acc = 0.f;
    #pragma unroll
    for (int k = 0; k < 50; ++k)
      acc += w2s[half * 50 + k] * tanhf(pr[k] + q[half * 50 + k]);
    acc += __shfl_xor(acc, 1);     // combine the two halves of this row
    const float sv = acc + bd2;    // logit; p>0.5 <=> sv>0
    __syncthreads();
    if (allowed && half == 0 && row >= seg && sv > 0.f)
      atomicMin(&firstpos, row);
    __syncthreads();
    const int fp = allowed ? firstpos : 512;
    const int lim = (fp < 512) ? fp : 511;
    if (half == 0 && row >= seg && row <= lim) {
      float p = 1.f / (1.f + expf(-sv));
      float term = (row == fp) ? p : (1.f - p);
      logp_part += logf(term * 0.99999f + 5e-6f);
      if (row == fp) selfl[row] = 1;
    }
    if (fp < 512) {
      if (tid < 100) q[tid] += Qb[(size_t)fp * 100 + tid];
      count += 1;
      seg = fp + 1;
    } else {
      seg = 512;
    }
    __syncthreads();
  }

  float v = logp_part;
  v += __shfl_xor(v, 1);  v += __shfl_xor(v, 2);  v += __shfl_xor(v, 4);
  v += __shfl_xor(v, 8);  v += __shfl_xor(v, 16); v += __shfl_xor(v, 32);
  if ((tid & 63) == 0) red[tid >> 6] = v;
  __syncthreads();
  if (tid == 0) {
    float s = 0.f;
    #pragma unroll
    for (int w = 0; w < 16; ++w) s += red[w];
    out[0] = s;
  }
  if (half == 0) out[1 + row] = (float)selfl[row];
}

// ---------------------------------------------------------------------------
// Launcher
// ---------------------------------------------------------------------------
extern "C" void kernel_launch(void* const* d_in, const int* in_sizes, int n_in,
                              void* d_out, int out_size, void* d_ws, size_t ws_size,
                              hipStream_t stream) {
  const int*   x      = (const int*)  d_in[0];
  const int*   nos    = (const int*)  d_in[1];
  const float* emb    = (const float*)d_in[2];
  const float* cw[8];
  for (int k = 0; k < 8; ++k) cw[k] = (const float*)d_in[3 + k];
  const float* conv_b = (const float*)d_in[11];
  const float* w_ih_f = (const float*)d_in[12];
  const float* w_hh_f = (const float*)d_in[13];
  const float* b_ih_f = (const float*)d_in[14];
  const float* b_hh_f = (const float*)d_in[15];
  const float* w_ih_b = (const float*)d_in[16];
  const float* w_hh_b = (const float*)d_in[17];
  const float* b_ih_b = (const float*)d_in[18];
  const float* b_hh_b = (const float*)d_in[19];
  const float* W_doc  = (const float*)d_in[20];
  const float* b_doc  = (const float*)d_in[21];
  const float* W_d1   = (const float*)d_in[22];
  const float* b_d1   = (const float*)d_in[23];
  const float* W_d2   = (const float*)d_in[24];
  const float* b_d2   = (const float*)d_in[25];
  const float* W_r    = (const float*)d_in[26];
  const float* b_r    = (const float*)d_in[27];

  float* ws = (float*)d_ws;
  const size_t OFF_POOLED  = 0;         // 512*400 (reused: hbuf after gi gemm)
  const size_t OFF_GI      = 204800;    // 512*2400 (reused as Qbuf later)
  const size_t OFF_ENC     = 1433600;   // 512*800
  const size_t OFF_R       = 1843200;   // 512*400
  const size_t OFF_PRE1    = 2048000;   // 512*100
  const size_t OFF_MEAN    = 2099200;   // 800
  const size_t OFF_DOC     = 2100000;   // 400
  const size_t OFF_DOCTERM = 2100400;   // 100 (+pad)
  float* pooled  = ws + OFF_POOLED;
  float* gi      = ws + OFF_GI;
  float* enc     = ws + OFF_ENC;
  float* Rbuf    = ws + OFF_R;
  float* pre1    = ws + OFF_PRE1;
  float* mean    = ws + OFF_MEAN;
  float* doc     = ws + OFF_DOC;
  float* docterm = ws + OFF_DOCTERM;
  float* Qbuf    = ws + OFF_GI;     // gi dead after GRU; reuse for Q
  // hbuf aliases the pooled region (dead after the gi GEMM): 2*2*400 u64 = 12.8 KB
  unsigned long long* hbuf = (unsigned long long*)(ws + OFF_POOLED);

  pooled_kernel<<<512, 256, 0, stream>>>(x, emb, cw[0], cw[1], cw[2], cw[3],
                                         cw[4], cw[5], cw[6], cw[7], conv_b, pooled);

  // gi = pooled @ [w_ih_f; w_ih_b]^T + bias  -> [512][2400]  (one launch)
  gemm_gi<<<dim3(38, 8), 256, 0, stream>>>(pooled, w_ih_f, b_ih_f, w_ih_b, b_ih_b, gi);

  // zero tagged h buffers (pooled region is dead now); tag 0 == h_0 = 0
  hipMemsetAsync(hbuf, 0, 1600 * sizeof(unsigned long long), stream);

  gru_scan_kernel<<<2 * GRU_NB, 256, 0, stream>>>(gi, w_hh_f, b_hh_f, w_hh_b, b_hh_b,
                                                  enc, hbuf);

  mean_kernel<<<50, 256, 0, stream>>>(enc, mean);
  doc_kernel<<<400, 64, 0, stream>>>(W_doc, b_doc, mean, doc);
  docterm_kernel<<<100, 64, 0, stream>>>(W_d1, b_d1, doc, docterm);

  // R = tanh(enc @ W_r^T + b_r)  [512][400]
  gemm32<1><<<dim3(13, 16), 256, 0, stream>>>(enc, 800, W_r, 800, b_r,
                                              Rbuf, 400, 512, 400, 800, 1);
  // Q = R @ W_d1[:,800:1200]^T  [512][100]
  gemm32<2><<<dim3(4, 16), 256, 0, stream>>>(Rbuf, 400, W_d1 + 800, 1600, nullptr,
                                             Qbuf, 100, 512, 100, 400, 0);
  // pre1 = enc @ W_d1[:, :800]^T + docterm  [512][100]
  gemm32<3><<<dim3(4, 16), 256, 0, stream>>>(enc, 800, W_d1, 1600, docterm,
                                             pre1, 100, 512, 100, 800, 0);

  decoder_kernel<<<1, 1024, 0, stream>>>(pre1, Qbuf, W_d2, b_d2, nos,
                                         (float*)d_out);
}

// Round 7
// 2077.860 us; speedup vs baseline: 1.9816x; 1.0386x over previous
//
#include <hip/hip_runtime.h>
#include <math.h>

// Problem dims
#define S_N   512
#define WL_N  100
#define E_N   200
#define OC_N  50
#define H_N   400

// ---------------------------------------------------------------------------
// K1: pooled[s][400] = conv_b + (1/L) * sum_{t<L} conv(emb[x])  via prefix sums
// Conv stage: one (K,oc) pair per WAVE -> coalesced weight reads.
// Prefix stage truncated at L+7 (only P[1..7] and P[L-7..L+7] are needed).
// ---------------------------------------------------------------------------
template<int K>
__device__ inline float conv_dot(const float* __restrict__ wbase,
                                 const float (*Ap)[17], int lane)
{
  constexpr int W = 2 * K + 1;
  constexpr int n = E_N * W;
  float acc = 0.f;
  for (int idx = lane; idx < n; idx += 64) {
    int e = idx / W;
    int k = idx - e * W;
    acc += wbase[idx] * Ap[e][7 - K + k];
  }
  return acc;
}

__global__ __launch_bounds__(256, 1)
void pooled_kernel(const int* __restrict__ x, const float* __restrict__ emb,
                   const float* __restrict__ cw0, const float* __restrict__ cw1,
                   const float* __restrict__ cw2, const float* __restrict__ cw3,
                   const float* __restrict__ cw4, const float* __restrict__ cw5,
                   const float* __restrict__ cw6, const float* __restrict__ cw7,
                   const float* __restrict__ conv_b, float* __restrict__ pooled)
{
  const int s = blockIdx.x;
  const int tid = threadIdx.x;
  __shared__ int xr[WL_N];
  __shared__ int Lsh;
  __shared__ float Apart[E_N][17];  // windowed sums, d+7 in [0,14]
  __shared__ float Bpart[E_N][9];   // prefix P[m], m=1..7
  if (tid < WL_N) xr[tid] = x[s * WL_N + tid];
  __syncthreads();
  if (tid == 0) {
    int L = 0;
    for (int t = 0; t < WL_N; ++t) L += (xr[t] != 0) ? 1 : 0;
    Lsh = L;
  }
  __syncthreads();
  const int L = Lsh;  // lengths in [20,100]
  const int Lp7 = (L + 7 < WL_N) ? (L + 7) : WL_N;
  if (tid < E_N) {
    const int e = tid;
    float acc = 0.f;
    for (int t = 0; t < Lp7; ++t) {
      acc += emb[(size_t)xr[t] * E_N + e];
      int m = t + 1;
      if (m <= 7) Bpart[e][m] = acc;                 // P[m], m=1..7
      int rel = m - (L - 7);
      if (rel >= 0 && rel < 15) Apart[e][rel] = acc; // P[L-7+rel]
    }
    const float accF = acc;  // P[Lp7]; equals P[100] whenever m>100 is reachable
    #pragma unroll
    for (int dd = 0; dd < 15; ++dd) {
      int m = L - 7 + dd;
      float A = (m > WL_N) ? accF : Apart[e][dd];
      int d = dd - 7;
      float B = (d > 0) ? Bpart[e][d] : 0.f;
      Apart[e][dd] = A - B;  // sum_{t<L} in[e][t+d], zero-padded
    }
  }
  __syncthreads();
  const float invL = 1.f / (float)L;
  const int wv = tid >> 6, lane = tid & 63;
  for (int p = wv; p < 400; p += 4) {
    const int K = p / 50, oc = p % 50;
    float acc = 0.f;
    switch (K) {
      case 0: acc = conv_dot<0>(cw0 + (size_t)oc * 200,  Apart, lane); break;
      case 1: acc = conv_dot<1>(cw1 + (size_t)oc * 600,  Apart, lane); break;
      case 2: acc = conv_dot<2>(cw2 + (size_t)oc * 1000, Apart, lane); break;
      case 3: acc = conv_dot<3>(cw3 + (size_t)oc * 1400, Apart, lane); break;
      case 4: acc = conv_dot<4>(cw4 + (size_t)oc * 1800, Apart, lane); break;
      case 5: acc = conv_dot<5>(cw5 + (size_t)oc * 2200, Apart, lane); break;
      case 6: acc = conv_dot<6>(cw6 + (size_t)oc * 2600, Apart, lane); break;
      case 7: acc = conv_dot<7>(cw7 + (size_t)oc * 3000, Apart, lane); break;
    }
    acc += __shfl_xor(acc, 1);  acc += __shfl_xor(acc, 2);
    acc += __shfl_xor(acc, 4);  acc += __shfl_xor(acc, 8);
    acc += __shfl_xor(acc, 16); acc += __shfl_xor(acc, 32);
    if (lane == 0)
      pooled[(size_t)s * 400 + p] = conv_b[p] + acc * invL;
  }
}

// ---------------------------------------------------------------------------
// K2: merged gi GEMM: gi[512][2400] = pooled @ [w_ih_f; w_ih_b]^T + biases
// ---------------------------------------------------------------------------
__global__ __launch_bounds__(256, 2)
void gemm_gi(const float* __restrict__ A,   // pooled [512][400]
             const float* __restrict__ wf, const float* __restrict__ bf,
             const float* __restrict__ wb, const float* __restrict__ bb,
             float* __restrict__ C)         // gi [512][2400]
{
  __shared__ float As[16][65];
  __shared__ float Bs[16][65];
  const int bm = blockIdx.y * 64, bn = blockIdx.x * 64;
  const int tid = threadIdx.x;
  const int tr = (tid / 16) * 4, tc = (tid % 16) * 4;
  float acc[4][4] = {};
  for (int k0 = 0; k0 < 400; k0 += 16) {
    for (int l = tid; l < 64 * 16; l += 256) {
      int r = l / 16, c = l % 16;
      As[c][r] = A[(size_t)(bm + r) * 400 + k0 + c];
    }
    for (int l = tid; l < 64 * 16; l += 256) {
      int r = l / 16, c = l % 16;
      int gcol = bn + r;
      float v = 0.f;
      if (gcol < 1200)      v = wf[(size_t)gcol * 400 + k0 + c];
      else if (gcol < 2400) v = wb[(size_t)(gcol - 1200) * 400 + k0 + c];
      Bs[c][r] = v;
    }
    __syncthreads();
    #pragma unroll
    for (int kk = 0; kk < 16; ++kk) {
      float a[4], b[4];
      #pragma unroll
      for (int u = 0; u < 4; ++u) { a[u] = As[kk][tr + u]; b[u] = Bs[kk][tc + u]; }
      #pragma unroll
      for (int u = 0; u < 4; ++u)
        #pragma unroll
        for (int v = 0; v < 4; ++v) acc[u][v] += a[u] * b[v];
    }
    __syncthreads();
  }
  for (int u = 0; u < 4; ++u) {
    int r = bm + tr + u;
    for (int v = 0; v < 4; ++v) {
      int c = bn + tc + v; if (c >= 2400) continue;
      float bias = (c < 1200) ? bf[c] : bb[c - 1200];
      C[(size_t)r * 2400 + c] = acc[u][v] + bias;
    }
  }
}

// ---------------------------------------------------------------------------
// 32x32-tile GEMM: C[M,N] = A[M,K] @ B[N,K]^T + bias[N] (optional tanh).
// ---------------------------------------------------------------------------
template<int TAG>
__global__ __launch_bounds__(256, 4)
void gemm32(const float* __restrict__ A, int lda,
            const float* __restrict__ Bw, int ldb,
            const float* __restrict__ bias,
            float* __restrict__ C, int ldc,
            int M, int N, int K, int act)
{
  __shared__ float As[32][33];
  __shared__ float Bs[32][33];
  const int bm = blockIdx.y * 32, bn = blockIdx.x * 32;
  const int tid = threadIdx.x;
  const int tr = (tid >> 4) * 2, tc = (tid & 15) * 2;
  float acc[2][2] = {};
  for (int k0 = 0; k0 < K; k0 += 32) {
    #pragma unroll
    for (int p = 0; p < 4; ++p) {
      int l = tid + p * 256;
      int r = l >> 5, c = l & 31;
      As[c][r] = (bm + r < M) ? A[(size_t)(bm + r) * lda + k0 + c] : 0.f;
      Bs[c][r] = (bn + r < N) ? Bw[(size_t)(bn + r) * ldb + k0 + c] : 0.f;
    }
    __syncthreads();
    #pragma unroll
    for (int kk = 0; kk < 32; ++kk) {
      float a0 = As[kk][tr], a1 = As[kk][tr + 1];
      float b0 = Bs[kk][tc], b1 = Bs[kk][tc + 1];
      acc[0][0] += a0 * b0; acc[0][1] += a0 * b1;
      acc[1][0] += a1 * b0; acc[1][1] += a1 * b1;
    }
    __syncthreads();
  }
  #pragma unroll
  for (int u = 0; u < 2; ++u) {
    int r = bm + tr + u; if (r >= M) continue;
    #pragma unroll
    for (int v = 0; v < 2; ++v) {
      int c = bn + tc + v; if (c >= N) continue;
      float xv = acc[u][v] + (bias ? bias[c] : 0.f);
      if (act == 1) xv = tanhf(xv);
      C[(size_t)r * ldc + c] = xv;
    }
  }
}

// ---------------------------------------------------------------------------
// K3: bidirectional GRU scan, 25 blocks x 256 threads per direction.
// Round-3 tagged-data protocol + ROLE-SPLIT WAVES:
//  - wave 0  : sole storer (h, enc, gi prefetch, mean accum). Never polls ->
//              its store ACKs never sit in a polling wave's vmcnt queue.
//  - waves1-3: pollers/stagers (2-deep pipelined tag poll). Never store.
// Gates route to wave 0 via ghs[48] LDS (+1 barrier). gi prefetched 2 steps
// ahead. Column-mean of enc folded in (mean_kernel eliminated).
// Safety induction unchanged: h(t+2) cannot be written anywhere before every
// block passed poll(t+1), which requires every block consumed step t.
// ---------------------------------------------------------------------------
#define GRU_NB 25
#define GRU_CHUNK 16
#define LDA64(p) __hip_atomic_load((p), __ATOMIC_RELAXED, __HIP_MEMORY_SCOPE_AGENT)
__global__ __launch_bounds__(256, 1)
void gru_scan_kernel(const float* __restrict__ gi,  // [512][2400] f|b
                     const float* __restrict__ whh_f, const float* __restrict__ bhh_f,
                     const float* __restrict__ whh_b, const float* __restrict__ bhh_b,
                     float* __restrict__ enc,                  // [512][800]
                     float* __restrict__ mean,                 // [800]
                     unsigned long long* __restrict__ hbuf)    // [2 dirs][2][400]
{
  const int tid = threadIdx.x;
  const int dir = blockIdx.x / GRU_NB;
  const int b   = blockIdx.x % GRU_NB;
  const float* whh = dir ? whh_b : whh_f;
  const float* bhh = dir ? bhh_b : bhh_f;
  unsigned long long* hb = hbuf + (size_t)dir * 800;
  const int i0 = b * GRU_CHUNK;

  __shared__ float wl[48][400];   // 76.8 KB
  __shared__ float hs[400];
  __shared__ float ghs[48];

  for (int l = tid; l < 48 * 400; l += 256) {
    int lr = l / 400, c = l % 400;
    int g = lr / GRU_CHUNK, ii = lr % GRU_CHUNK;
    wl[lr][c] = whh[(size_t)(g * 400 + i0 + ii) * 400 + c];
  }

  const int i  = tid >> 4;   // 0..15: h-index within our chunk (dot stage)
  const int cc = tid & 15;   // 0..15: column chunk (dot stage)
  const int c0 = cc * 25;

  // wave-0 lanes 0..15: h-compute state
  float blr = 0.f, blz = 0.f, bln = 0.f, msum = 0.f;
  float g0r = 0.f, g0z = 0.f, g0n = 0.f;   // gi for step t
  float g1r = 0.f, g1z = 0.f, g1n = 0.f;   // gi for step t+1
  if (tid < GRU_CHUNK) {
    blr = bhh[i0 + tid];
    blz = bhh[400 + i0 + tid];
    bln = bhh[800 + i0 + tid];
    {
      int t0 = dir ? 511 : 0;
      const float* g = gi + (size_t)t0 * 2400 + dir * 1200 + i0 + tid;
      g0r = g[0]; g0z = g[400]; g0n = g[800];
      int t1 = dir ? 510 : 1;
      g = gi + (size_t)t1 * 2400 + dir * 1200 + i0 + tid;
      g1r = g[0]; g1z = g[400]; g1n = g[800];
    }
  }
  __syncthreads();

  // poller geometry (waves 1..3; 192 threads cover 400 words)
  const int p = tid - 64;                  // valid when tid >= 64
  const bool h2 = (p >= 0) && (p < 16);    // third word p+384

  for (int t = 0; t < 512; ++t) {
    const int t_in = dir ? (511 - t) : t;
    // ---- waves 1-3: 2-deep pipelined tag poll + stage to hs ----
    if (tid >= 64) {
      const unsigned long long* src = hb + (t & 1) * 400;
      const unsigned want = (unsigned)t;
      unsigned long long a0, a1, a2 = 0, b0, b1, b2 = 0, r0, r1, r2 = 0;
      a0 = LDA64(src + p); a1 = LDA64(src + p + 192); if (h2) a2 = LDA64(src + p + 384);
      b0 = LDA64(src + p); b1 = LDA64(src + p + 192); if (h2) b2 = LDA64(src + p + 384);
      for (;;) {
        bool ok = ((unsigned)(a0 >> 32) == want) && ((unsigned)(a1 >> 32) == want)
                  && (!h2 || ((unsigned)(a2 >> 32) == want));
        if (__all(ok)) { r0 = a0; r1 = a1; r2 = a2; break; }
        a0 = LDA64(src + p); a1 = LDA64(src + p + 192); if (h2) a2 = LDA64(src + p + 384);
        ok = ((unsigned)(b0 >> 32) == want) && ((unsigned)(b1 >> 32) == want)
             && (!h2 || ((unsigned)(b2 >> 32) == want));
        if (__all(ok)) { r0 = b0; r1 = b1; r2 = b2; break; }
        b0 = LDA64(src + p); b1 = LDA64(src + p + 192); if (h2) b2 = LDA64(src + p + 384);
      }
      hs[p] = __uint_as_float((unsigned)r0);
      hs[p + 192] = __uint_as_float((unsigned)r1);
      if (h2) hs[p + 384] = __uint_as_float((unsigned)r2);
    }
    __syncthreads();   // [1] hs ready

    // ---- all waves: 3 gate partial dots over our 25-column chunk ----
    float a0 = 0.f, a1 = 0.f, a2 = 0.f;
    #pragma unroll
    for (int j = 0; j < 25; ++j) {
      float hv = hs[c0 + j];
      a0 += wl[i][c0 + j] * hv;
      a1 += wl[16 + i][c0 + j] * hv;
      a2 += wl[32 + i][c0 + j] * hv;
    }
    #pragma unroll
    for (int m = 1; m <= 8; m <<= 1) {
      a0 += __shfl_xor(a0, m);
      a1 += __shfl_xor(a1, m);
      a2 += __shfl_xor(a2, m);
    }
    if (cc == 0) { ghs[i] = a0; ghs[16 + i] = a1; ghs[32 + i] = a2; }
    __syncthreads();   // [2] ghs ready

    // ---- wave 0 (lanes 0..15): h compute + ALL stores + gi prefetch ----
    if (tid < GRU_CHUNK) {
      float r = 1.f / (1.f + expf(-(g0r + ghs[tid] + blr)));
      float z = 1.f / (1.f + expf(-(g0z + ghs[16 + tid] + blz)));
      float n = tanhf(g0n + r * (ghs[32 + tid] + bln));
      float hprev = hs[i0 + tid];
      float hn = (1.f - z) * n + z * hprev;
      msum += hn;
      unsigned long long pk =
          ((unsigned long long)(unsigned)(t + 1) << 32) |
          (unsigned long long)__float_as_uint(hn);
      __hip_atomic_store(hb + ((t + 1) & 1) * 400 + i0 + tid, pk,
                         __ATOMIC_RELAXED, __HIP_MEMORY_SCOPE_AGENT);
      enc[(size_t)t_in * 800 + dir * 400 + i0 + tid] = hn;
      // rotate gi pipeline and prefetch step t+2
      g0r = g1r; g0z = g1z; g0n = g1n;
      int t2 = t + 2; if (t2 > 511) t2 = 511;
      int tn2 = dir ? (511 - t2) : t2;
      const float* g = gi + (size_t)tn2 * 2400 + dir * 1200 + i0 + tid;
      g1r = g[0]; g1z = g[400]; g1n = g[800];
    }
    // no trailing barrier: hs/ghs of step t can only be overwritten after
    // every block passed poll(t+1), which requires our wave 0 published t+1.
  }
  if (tid < GRU_CHUNK)
    mean[dir * 400 + i0 + tid] = msum * (1.f / 512.f);
}

// K4b: doc[r] = tanh(W_doc[r]·mean + b_doc[r]); one block (64 lanes) per row
__global__ void doc_kernel(const float* __restrict__ W_doc, const float* __restrict__ b_doc,
                           const float* __restrict__ mean, float* __restrict__ doc)
{
  int r = blockIdx.x, lane = threadIdx.x;
  float s = 0.f;
  for (int k = lane; k < 800; k += 64) s += W_doc[(size_t)r * 800 + k] * mean[k];
  s += __shfl_xor(s, 1);  s += __shfl_xor(s, 2);  s += __shfl_xor(s, 4);
  s += __shfl_xor(s, 8);  s += __shfl_xor(s, 16); s += __shfl_xor(s, 32);
  if (lane == 0) doc[r] = tanhf(s + b_doc[r]);
}

// K4c: docterm[r] = W_d1[r,1200:1600]·doc + b_d1[r]
__global__ void docterm_kernel(const float* __restrict__ W_d1, const float* __restrict__ b_d1,
                               const float* __restrict__ doc, float* __restrict__ docterm)
{
  int r = blockIdx.x, lane = threadIdx.x;
  float s = 0.f;
  for (int k = lane; k < 400; k += 64) s += W_d1[(size_t)r * 1600 + 1200 + k] * doc[k];
  s += __shfl_xor(s, 1);  s += __shfl_xor(s, 2);  s += __shfl_xor(s, 4);
  s += __shfl_xor(s, 8);  s += __shfl_xor(s, 16); s += __shfl_xor(s, 32);
  if (lane == 0) docterm[r] = s + b_d1[r];
}

// ---------------------------------------------------------------------------
// K6: decoder via parallel segment passes (q constant between selections;
// <= num_of_sent selections -> few passes). 1 block x 1024 threads.
// ---------------------------------------------------------------------------
__global__ __launch_bounds__(1024, 1)
void decoder_kernel(const float* __restrict__ pre1,  // [512][100]
                    const float* __restrict__ Qb,    // [512][100]
                    const float* __restrict__ W_d2,  // [100]
                    const float* __restrict__ b_d2,  // [1]
                    const int* __restrict__ nos_p,
                    float* __restrict__ out)         // [513]: logp, sels
{
  const int tid = threadIdx.x;
  const int row = tid >> 1;
  const int half = tid & 1;
  __shared__ float q[100];
  __shared__ float w2s[100];
  __shared__ int   selfl[512];
  __shared__ int   firstpos;
  __shared__ float red[16];
  if (tid < 100) { q[tid] = 0.f; w2s[tid] = W_d2[tid]; }
  if (tid < 512) selfl[tid] = 0;
  float pr[50];
  #pragma unroll
  for (int k = 0; k < 50; ++k) pr[k] = pre1[(size_t)row * 100 + half * 50 + k];
  const float bd2 = b_d2[0];
  const int nos = nos_p[0];
  int count = 0, seg = 0;
  float logp_part = 0.f;
  __syncthreads();

  for (int pass = 0; pass < 600 && seg < 512; ++pass) {
    const bool allowed = (nos <= 0) || (count < nos);
    if (tid == 0) firstpos = 512;
    float acc = 0.f;
    #pragma unroll
    for (int k = 0; k < 50; ++k)
      acc += w2s[half * 50 + k] * tanhf(pr[k] + q[half * 50 + k]);
    acc += __shfl_xor(acc, 1);     // combine the two halves of this row
    const float sv = acc + bd2;    // logit; p>0.5 <=> sv>0
    __syncthreads();
    if (allowed && half == 0 && row >= seg && sv > 0.f)
      atomicMin(&firstpos, row);
    __syncthreads();
    const int fp = allowed ? firstpos : 512;
    const int lim = (fp < 512) ? fp : 511;
    if (half == 0 && row >= seg && row <= lim) {
      float p = 1.f / (1.f + expf(-sv));
      float term = (row == fp) ? p : (1.f - p);
      logp_part += logf(term * 0.99999f + 5e-6f);
      if (row == fp) selfl[row] = 1;
    }
    if (fp < 512) {
      if (tid < 100) q[tid] += Qb[(size_t)fp * 100 + tid];
      count += 1;
      seg = fp + 1;
    } else {
      seg = 512;
    }
    __syncthreads();
  }

  float v = logp_part;
  v += __shfl_xor(v, 1);  v += __shfl_xor(v, 2);  v += __shfl_xor(v, 4);
  v += __shfl_xor(v, 8);  v += __shfl_xor(v, 16); v += __shfl_xor(v, 32);
  if ((tid & 63) == 0) red[tid >> 6] = v;
  __syncthreads();
  if (tid == 0) {
    float s = 0.f;
    #pragma unroll
    for (int w = 0; w < 16; ++w) s += red[w];
    out[0] = s;
  }
  if (half == 0) out[1 + row] = (float)selfl[row];
}

// ---------------------------------------------------------------------------
// Launcher
// ---------------------------------------------------------------------------
extern "C" void kernel_launch(void* const* d_in, const int* in_sizes, int n_in,
                              void* d_out, int out_size, void* d_ws, size_t ws_size,
                              hipStream_t stream) {
  const int*   x      = (const int*)  d_in[0];
  const int*   nos    = (const int*)  d_in[1];
  const float* emb    = (const float*)d_in[2];
  const float* cw[8];
  for (int k = 0; k < 8; ++k) cw[k] = (const float*)d_in[3 + k];
  const float* conv_b = (const float*)d_in[11];
  const float* w_ih_f = (const float*)d_in[12];
  const float* w_hh_f = (const float*)d_in[13];
  const float* b_ih_f = (const float*)d_in[14];
  const float* b_hh_f = (const float*)d_in[15];
  const float* w_ih_b = (const float*)d_in[16];
  const float* w_hh_b = (const float*)d_in[17];
  const float* b_ih_b = (const float*)d_in[18];
  const float* b_hh_b = (const float*)d_in[19];
  const float* W_doc  = (const float*)d_in[20];
  const float* b_doc  = (const float*)d_in[21];
  const float* W_d1   = (const float*)d_in[22];
  const float* b_d1   = (const float*)d_in[23];
  const float* W_d2   = (const float*)d_in[24];
  const float* b_d2   = (const float*)d_in[25];
  const float* W_r    = (const float*)d_in[26];
  const float* b_r    = (const float*)d_in[27];

  float* ws = (float*)d_ws;
  const size_t OFF_POOLED  = 0;         // 512*400 (reused: hbuf after gi gemm)
  const size_t OFF_GI      = 204800;    // 512*2400 (reused as Qbuf later)
  const size_t OFF_ENC     = 1433600;   // 512*800
  const size_t OFF_R       = 1843200;   // 512*400
  const size_t OFF_PRE1    = 2048000;   // 512*100
  const size_t OFF_MEAN    = 2099200;   // 800
  const size_t OFF_DOC     = 2100000;   // 400
  const size_t OFF_DOCTERM = 2100400;   // 100 (+pad)
  float* pooled  = ws + OFF_POOLED;
  float* gi      = ws + OFF_GI;
  float* enc     = ws + OFF_ENC;
  float* Rbuf    = ws + OFF_R;
  float* pre1    = ws + OFF_PRE1;
  float* mean    = ws + OFF_MEAN;
  float* doc     = ws + OFF_DOC;
  float* docterm = ws + OFF_DOCTERM;
  float* Qbuf    = ws + OFF_GI;     // gi dead after GRU; reuse for Q
  // hbuf aliases the pooled region (dead after the gi GEMM): 2*2*400 u64 = 12.8 KB
  unsigned long long* hbuf = (unsigned long long*)(ws + OFF_POOLED);

  pooled_kernel<<<512, 256, 0, stream>>>(x, emb, cw[0], cw[1], cw[2], cw[3],
                                         cw[4], cw[5], cw[6], cw[7], conv_b, pooled);

  // gi = pooled @ [w_ih_f; w_ih_b]^T + bias  -> [512][2400]  (one launch)
  gemm_gi<<<dim3(38, 8), 256, 0, stream>>>(pooled, w_ih_f, b_ih_f, w_ih_b, b_ih_b, gi);

  // zero tagged h buffers (pooled region is dead now); tag 0 == h_0 = 0
  hipMemsetAsync(hbuf, 0, 1600 * sizeof(unsigned long long), stream);

  gru_scan_kernel<<<2 * GRU_NB, 256, 0, stream>>>(gi, w_hh_f, b_hh_f, w_hh_b, b_hh_b,
                                                  enc, mean, hbuf);

  doc_kernel<<<400, 64, 0, stream>>>(W_doc, b_doc, mean, doc);
  docterm_kernel<<<100, 64, 0, stream>>>(W_d1, b_d1, doc, docterm);

  // R = tanh(enc @ W_r^T + b_r)  [512][400]
  gemm32<1><<<dim3(13, 16), 256, 0, stream>>>(enc, 800, W_r, 800, b_r,
                                              Rbuf, 400, 512, 400, 800, 1);
  // Q = R @ W_d1[:,800:1200]^T  [512][100]
  gemm32<2><<<dim3(4, 16), 256, 0, stream>>>(Rbuf, 400, W_d1 + 800, 1600, nullptr,
                                             Qbuf, 100, 512, 100, 400, 0);
  // pre1 = enc @ W_d1[:, :800]^T + docterm  [512][100]
  gemm32<3><<<dim3(4, 16), 256, 0, stream>>>(enc, 800, W_d1, 1600, docterm,
                                             pre1, 100, 512, 100, 800, 0);

  decoder_kernel<<<1, 1024, 0, stream>>>(pre1, Qbuf, W_d2, b_d2, nos,
                                         (float*)d_out);
}